// Round 1
// baseline (97.030 us; speedup 1.0000x reference)
//
#include <hip/hip_runtime.h>
#include <math.h>

#define DEVFN __device__ __forceinline__

DEVFN float shxor(float v, int m) { return __shfl_xor(v, m, 64); }

// ---------------------------------------------------------------------------
// Precompute the 16 Rot gate matrices (depend only on q_weights) into d_ws.
// Layout: gate g = l*8 + wire, 8 floats: U00r,U00i,U01r,U01i,U10r,U10i,U11r,U11i
// Rot = RZ(omega) RY(theta) RZ(phi):
//   U = [[ep*c, -conj(em)*s], [em*s, conj(ep)*c]]
//   ep = exp(-0.5i(phi+omega)), em = exp(-0.5i(phi-omega))
// ---------------------------------------------------------------------------
__global__ void prep_gates(const float* __restrict__ qw, float* __restrict__ gw) {
  int g = threadIdx.x;
  if (g >= 16) return;
  int l = g >> 3, i = g & 7;
  float phi = qw[l*24 + i*3 + 0];
  float th  = qw[l*24 + i*3 + 1];
  float om  = qw[l*24 + i*3 + 2];
  float c = cosf(0.5f*th), s = sinf(0.5f*th);
  float ap = 0.5f*(phi+om), am = 0.5f*(phi-om);
  float epr = cosf(ap), epi = -sinf(ap);
  float emr = cosf(am), emi = -sinf(am);
  float* u = gw + g*8;
  u[0] =  epr*c;  u[1] =  epi*c;    // U00 = ep*c
  u[2] = -emr*s;  u[3] =  emi*s;    // U01 = -conj(em)*s
  u[4] =  emr*s;  u[5] =  emi*s;    // U10 = em*s
  u[6] =  epr*c;  u[7] = -epi*c;    // U11 = conj(ep)*c
}

// ---------------------------------------------------------------------------
// State layout: amplitude index a (8 bits) = lane*4 + k.
//   wire w <-> bit p = 7 - w of a.
//   p in [2,7]  -> lane bit (p-2)   (wires 0..5 -> lane bit 5-w)
//   p in [0,1]  -> k bit p          (wires 6,7)
// ---------------------------------------------------------------------------

template<int W>
DEVFN void rot_gate(int lane, float (&sr)[4], float (&si)[4], const float* __restrict__ u) {
  const float u00r=u[0], u00i=u[1], u01r=u[2], u01i=u[3];
  const float u10r=u[4], u10i=u[5], u11r=u[6], u11i=u[7];
  if constexpr (W <= 5) {
    constexpr int M = 1 << (5 - W);
    const bool hi = (lane & M) != 0;
    // my-new = cm*mine + co*other
    const float cmr = hi ? u11r : u00r, cmi = hi ? u11i : u00i;
    const float cor = hi ? u10r : u01r, coi = hi ? u10i : u01i;
    #pragma unroll
    for (int k = 0; k < 4; ++k) {
      float orr = shxor(sr[k], M);
      float oii = shxor(si[k], M);
      float nr = cmr*sr[k] - cmi*si[k] + cor*orr - coi*oii;
      float ni = cmr*si[k] + cmi*sr[k] + cor*oii + coi*orr;
      sr[k] = nr; si[k] = ni;
    }
  } else {
    constexpr int KB = (W == 6) ? 2 : 1;   // in-lane pair bit
    #pragma unroll
    for (int k0 = 0; k0 < 4; ++k0) {
      if ((k0 & KB) == 0) {
        const int k1 = k0 | KB;
        float ar = sr[k0], ai = si[k0];
        float br = sr[k1], bi = si[k1];
        sr[k0] = u00r*ar - u00i*ai + u01r*br - u01i*bi;
        si[k0] = u00r*ai + u00i*ar + u01r*bi + u01i*br;
        sr[k1] = u10r*ar - u10i*ai + u11r*br - u11i*bi;
        si[k1] = u10r*ai + u10i*ar + u11r*bi + u11i*br;
      }
    }
  }
}

template<int C, int T>
DEVFN void cnot_gate(int lane, float (&sr)[4], float (&si)[4]) {
  constexpr int PC = 7 - C, PT = 7 - T;
  if constexpr (PT >= 2) {
    constexpr int M = 1 << (PT - 2);
    #pragma unroll
    for (int k = 0; k < 4; ++k) {
      float orr = shxor(sr[k], M);
      float oii = shxor(si[k], M);
      bool ctrl;
      if constexpr (PC >= 2) ctrl = ((lane >> (PC - 2)) & 1) != 0;
      else                   ctrl = ((k >> PC) & 1) != 0;
      if (ctrl) { sr[k] = orr; si[k] = oii; }
    }
  } else {
    float tr[4], ti[4];
    #pragma unroll
    for (int k = 0; k < 4; ++k) { tr[k] = sr[k]; ti[k] = si[k]; }
    #pragma unroll
    for (int k = 0; k < 4; ++k) {
      bool ctrl;
      if constexpr (PC >= 2) ctrl = ((lane >> (PC - 2)) & 1) != 0;
      else                   ctrl = ((k >> PC) & 1) != 0;
      if (ctrl) { sr[k] = tr[k ^ (1 << PT)]; si[k] = ti[k ^ (1 << PT)]; }
    }
  }
}

__global__ __launch_bounds__(256) void qsb_main(
    const float* __restrict__ pca, const float* __restrict__ gw,
    const float* __restrict__ Wm, const float* __restrict__ bias,
    const float* __restrict__ gamma, const float* __restrict__ beta,
    float* __restrict__ out, int B) {
  int b    = (int)((blockIdx.x * blockDim.x + threadIdx.x) >> 6);
  int lane = (int)(threadIdx.x & 63);
  if (b >= B) return;

  // ---- AngleEmbedding: product state [cos(a/2), sin(a/2)] per wire ----
  float x = 0.f;
  if (lane < 8) x = pca[b*8 + lane];
  float ang = 1.5707963267948966f / (1.f + expf(-x));  // 0.5*pi*sigmoid(x)
  float cv = cosf(ang), sv = sinf(ang);

  float P = 1.f;
  #pragma unroll
  for (int w = 0; w < 6; ++w) {
    float cw = __shfl(cv, w, 64);
    float sw = __shfl(sv, w, 64);
    P *= (((lane >> (5 - w)) & 1) != 0) ? sw : cw;
  }
  float c6 = __shfl(cv, 6, 64), s6 = __shfl(sv, 6, 64);
  float c7 = __shfl(cv, 7, 64), s7 = __shfl(sv, 7, 64);

  float sr[4], si[4];
  sr[0] = P*c6*c7; sr[1] = P*c6*s7; sr[2] = P*s6*c7; sr[3] = P*s6*s7;
  si[0] = 0.f; si[1] = 0.f; si[2] = 0.f; si[3] = 0.f;

  // ---- Layer 0: Rot on each wire, then CNOT ring r=1 ----
  rot_gate<0>(lane, sr, si, gw + 0*8);
  rot_gate<1>(lane, sr, si, gw + 1*8);
  rot_gate<2>(lane, sr, si, gw + 2*8);
  rot_gate<3>(lane, sr, si, gw + 3*8);
  rot_gate<4>(lane, sr, si, gw + 4*8);
  rot_gate<5>(lane, sr, si, gw + 5*8);
  rot_gate<6>(lane, sr, si, gw + 6*8);
  rot_gate<7>(lane, sr, si, gw + 7*8);
  cnot_gate<0,1>(lane, sr, si);
  cnot_gate<1,2>(lane, sr, si);
  cnot_gate<2,3>(lane, sr, si);
  cnot_gate<3,4>(lane, sr, si);
  cnot_gate<4,5>(lane, sr, si);
  cnot_gate<5,6>(lane, sr, si);
  cnot_gate<6,7>(lane, sr, si);
  cnot_gate<7,0>(lane, sr, si);

  // ---- Layer 1: Rot on each wire, then CNOT ring r=2 ----
  rot_gate<0>(lane, sr, si, gw + (8+0)*8);
  rot_gate<1>(lane, sr, si, gw + (8+1)*8);
  rot_gate<2>(lane, sr, si, gw + (8+2)*8);
  rot_gate<3>(lane, sr, si, gw + (8+3)*8);
  rot_gate<4>(lane, sr, si, gw + (8+4)*8);
  rot_gate<5>(lane, sr, si, gw + (8+5)*8);
  rot_gate<6>(lane, sr, si, gw + (8+6)*8);
  rot_gate<7>(lane, sr, si, gw + (8+7)*8);
  cnot_gate<0,2>(lane, sr, si);
  cnot_gate<1,3>(lane, sr, si);
  cnot_gate<2,4>(lane, sr, si);
  cnot_gate<3,5>(lane, sr, si);
  cnot_gate<4,6>(lane, sr, si);
  cnot_gate<5,7>(lane, sr, si);
  cnot_gate<6,0>(lane, sr, si);
  cnot_gate<7,1>(lane, sr, si);

  // ---- Measurement: <Z_w> = sum_a |amp_a|^2 * (-1)^{bit_{7-w}(a)} ----
  float p0 = sr[0]*sr[0] + si[0]*si[0];
  float p1 = sr[1]*sr[1] + si[1]*si[1];
  float p2 = sr[2]*sr[2] + si[2]*si[2];
  float p3 = sr[3]*sr[3] + si[3]*si[3];
  float psum = (p0 + p1) + (p2 + p3);

  float z[8];
  #pragma unroll
  for (int w = 0; w < 6; ++w)
    z[w] = (((lane >> (5 - w)) & 1) != 0) ? -psum : psum;
  z[6] = (p0 + p1) - (p2 + p3);  // k bit1 (wire 6)
  z[7] = (p0 + p2) - (p1 + p3);  // k bit0 (wire 7)

  #pragma unroll
  for (int off = 1; off < 64; off <<= 1) {
    #pragma unroll
    for (int w = 0; w < 8; ++w) z[w] += shxor(z[w], off);
  }

  // ---- FC (8->64): lane j owns output column j ----
  float h = bias[lane];
  #pragma unroll
  for (int i = 0; i < 8; ++i) h = fmaf(z[i], Wm[i*64 + lane], h);

  // ---- LayerNorm over 64 (= the wave) ----
  float mu = h;
  #pragma unroll
  for (int off = 1; off < 64; off <<= 1) mu += shxor(mu, off);
  mu *= 0.015625f;
  float d = h - mu;
  float v = d * d;
  #pragma unroll
  for (int off = 1; off < 64; off <<= 1) v += shxor(v, off);
  v *= 0.015625f;
  float hn = d * rsqrtf(v + 1e-5f) * gamma[lane] + beta[lane];

  // ---- exact GELU ----
  float ge = 0.5f * hn * (1.f + erff(hn * 0.70710678118654752f));
  out[b*64 + lane] = ge;
}

extern "C" void kernel_launch(void* const* d_in, const int* in_sizes, int n_in,
                              void* d_out, int out_size, void* d_ws, size_t ws_size,
                              hipStream_t stream) {
  const float* pca   = (const float*)d_in[0];
  const float* qw    = (const float*)d_in[1];
  const float* Wm    = (const float*)d_in[2];
  const float* bias  = (const float*)d_in[3];
  const float* gamma = (const float*)d_in[4];
  const float* beta  = (const float*)d_in[5];
  float* out = (float*)d_out;
  float* gw  = (float*)d_ws;   // 128 floats = 512 B of scratch

  int B = in_sizes[0] / 8;

  hipLaunchKernelGGL(prep_gates, dim3(1), dim3(64), 0, stream, qw, gw);
  int blocks = (B + 3) / 4;    // 4 waves (batch elements) per 256-thread block
  hipLaunchKernelGGL(qsb_main, dim3(blocks), dim3(256), 0, stream,
                     pca, gw, Wm, bias, gamma, beta, out, B);
}

// Round 3
// 68.854 us; speedup vs baseline: 1.4092x; 1.4092x over previous
//
#include <hip/hip_runtime.h>
#include <math.h>

#define DEVFN __device__ __forceinline__

typedef __attribute__((ext_vector_type(8))) _Float16 f16x8;
typedef __attribute__((ext_vector_type(4))) float f32x4;

DEVFN float shxor(float v, int m) { return __shfl_xor(v, m, 64); }

// ---------------------------------------------------------------------------
// Gate machinery (verified in round 1).
// State layout: amplitude index a (8 bits) = lane*4 + k; wire w <-> bit 7-w.
//   bits 7..2 -> lane bits 5..0 ; bits 1..0 -> k bits 1..0
// ---------------------------------------------------------------------------
template<int W>
DEVFN void rot_gate(int lane, float (&sr)[4], float (&si)[4], const float* u) {
  const float u00r=u[0], u00i=u[1], u01r=u[2], u01i=u[3];
  const float u10r=u[4], u10i=u[5], u11r=u[6], u11i=u[7];
  if constexpr (W <= 5) {
    constexpr int M = 1 << (5 - W);
    const bool hi = (lane & M) != 0;
    const float cmr = hi ? u11r : u00r, cmi = hi ? u11i : u00i;
    const float cor = hi ? u10r : u01r, coi = hi ? u10i : u01i;
    #pragma unroll
    for (int k = 0; k < 4; ++k) {
      float orr = shxor(sr[k], M);
      float oii = shxor(si[k], M);
      float nr = cmr*sr[k] - cmi*si[k] + cor*orr - coi*oii;
      float ni = cmr*si[k] + cmi*sr[k] + cor*oii + coi*orr;
      sr[k] = nr; si[k] = ni;
    }
  } else {
    constexpr int KB = (W == 6) ? 2 : 1;
    #pragma unroll
    for (int k0 = 0; k0 < 4; ++k0) {
      if ((k0 & KB) == 0) {
        const int k1 = k0 | KB;
        float ar = sr[k0], ai = si[k0];
        float br = sr[k1], bi = si[k1];
        sr[k0] = u00r*ar - u00i*ai + u01r*br - u01i*bi;
        si[k0] = u00r*ai + u00i*ar + u01r*bi + u01i*br;
        sr[k1] = u10r*ar - u10i*ai + u11r*br - u11i*bi;
        si[k1] = u10r*ai + u10i*ar + u11r*bi + u11i*br;
      }
    }
  }
}

template<int C, int T>
DEVFN void cnot_gate(int lane, float (&sr)[4], float (&si)[4]) {
  constexpr int PC = 7 - C, PT = 7 - T;
  if constexpr (PT >= 2) {
    constexpr int M = 1 << (PT - 2);
    #pragma unroll
    for (int k = 0; k < 4; ++k) {
      float orr = shxor(sr[k], M);
      float oii = shxor(si[k], M);
      bool ctrl;
      if constexpr (PC >= 2) ctrl = ((lane >> (PC - 2)) & 1) != 0;
      else                   ctrl = ((k >> PC) & 1) != 0;
      if (ctrl) { sr[k] = orr; si[k] = oii; }
    }
  } else {
    float tr[4], ti[4];
    #pragma unroll
    for (int k = 0; k < 4; ++k) { tr[k] = sr[k]; ti[k] = si[k]; }
    #pragma unroll
    for (int k = 0; k < 4; ++k) {
      bool ctrl;
      if constexpr (PC >= 2) ctrl = ((lane >> (PC - 2)) & 1) != 0;
      else                   ctrl = ((k >> PC) & 1) != 0;
      if (ctrl) { sr[k] = tr[k ^ (1 << PT)]; si[k] = ti[k ^ (1 << PT)]; }
    }
  }
}

template<int W>
DEVFN void rot_qw(int lane, float (&sr)[4], float (&si)[4],
                  const float* __restrict__ qw, int l) {
  float phi = qw[l*24 + W*3 + 0];
  float th  = qw[l*24 + W*3 + 1];
  float om  = qw[l*24 + W*3 + 2];
  float c = cosf(0.5f*th), s = sinf(0.5f*th);
  float ap = 0.5f*(phi+om), am = 0.5f*(phi-om);
  float u[8];
  u[0] =  cosf(ap)*c; u[1] = -sinf(ap)*c;   // U00 = ep*c
  u[2] = -cosf(am)*s; u[3] = -sinf(am)*s;   // U01 = -conj(em)*s
  u[4] =  cosf(am)*s; u[5] = -sinf(am)*s;   // U10 = em*s
  u[6] =  cosf(ap)*c; u[7] =  sinf(ap)*c;   // U11 = conj(ep)*c
  rot_gate<W>(lane, sr, si, u);
}

// ---------------------------------------------------------------------------
// Prep: blocks 0..255 each compute one column j of the total circuit unitary U
// (by simulating basis state e_j) and store Bt[n][k]: n<256 -> Re U[n][j=k],
// n>=256 -> Im U[n-256][j=k], fp16, row-major [512][256].
// Block 256 computes folded LayerNorm/FC stats:
//   stats[0..7]=colmean(W), [8..15]=2*W·b/64, [16..79]=W·Wt/64, [80]=mean(b),
//   [81]=mean(b^2)
// ---------------------------------------------------------------------------
__global__ __launch_bounds__(64) void qsb_prep(
    const float* __restrict__ qw, const float* __restrict__ Wm,
    const float* __restrict__ bias,
    _Float16* __restrict__ Bt, float* __restrict__ stats) {
  int bid = blockIdx.x;
  int lane = threadIdx.x;
  if (bid < 256) {
    int col = bid;
    float sr[4], si[4];
    #pragma unroll
    for (int k = 0; k < 4; ++k) { sr[k] = (lane*4 + k == col) ? 1.f : 0.f; si[k] = 0.f; }
    // layer 0
    rot_qw<0>(lane, sr, si, qw, 0);
    rot_qw<1>(lane, sr, si, qw, 0);
    rot_qw<2>(lane, sr, si, qw, 0);
    rot_qw<3>(lane, sr, si, qw, 0);
    rot_qw<4>(lane, sr, si, qw, 0);
    rot_qw<5>(lane, sr, si, qw, 0);
    rot_qw<6>(lane, sr, si, qw, 0);
    rot_qw<7>(lane, sr, si, qw, 0);
    cnot_gate<0,1>(lane, sr, si);
    cnot_gate<1,2>(lane, sr, si);
    cnot_gate<2,3>(lane, sr, si);
    cnot_gate<3,4>(lane, sr, si);
    cnot_gate<4,5>(lane, sr, si);
    cnot_gate<5,6>(lane, sr, si);
    cnot_gate<6,7>(lane, sr, si);
    cnot_gate<7,0>(lane, sr, si);
    // layer 1 (ring r=2)
    rot_qw<0>(lane, sr, si, qw, 1);
    rot_qw<1>(lane, sr, si, qw, 1);
    rot_qw<2>(lane, sr, si, qw, 1);
    rot_qw<3>(lane, sr, si, qw, 1);
    rot_qw<4>(lane, sr, si, qw, 1);
    rot_qw<5>(lane, sr, si, qw, 1);
    rot_qw<6>(lane, sr, si, qw, 1);
    rot_qw<7>(lane, sr, si, qw, 1);
    cnot_gate<0,2>(lane, sr, si);
    cnot_gate<1,3>(lane, sr, si);
    cnot_gate<2,4>(lane, sr, si);
    cnot_gate<3,5>(lane, sr, si);
    cnot_gate<4,6>(lane, sr, si);
    cnot_gate<5,7>(lane, sr, si);
    cnot_gate<6,0>(lane, sr, si);
    cnot_gate<7,1>(lane, sr, si);
    #pragma unroll
    for (int k = 0; k < 4; ++k) {
      int a = lane*4 + k;
      Bt[a*256 + col]         = (_Float16)sr[k];
      Bt[(256 + a)*256 + col] = (_Float16)si[k];
    }
  } else {
    int t = lane;
    {
      int i = t >> 3, j = t & 7;
      float s = 0.f;
      for (int c = 0; c < 64; ++c) s += Wm[i*64 + c] * Wm[j*64 + c];
      stats[16 + t] = s * 0.015625f;
    }
    if (t < 8) {
      float s = 0.f, sb = 0.f;
      for (int c = 0; c < 64; ++c) { float w = Wm[t*64 + c]; s += w; sb += w * bias[c]; }
      stats[t]     = s * 0.015625f;
      stats[8 + t] = 2.f * sb * 0.015625f;
    }
    if (t == 0) {
      float s = 0.f, s2 = 0.f;
      for (int c = 0; c < 64; ++c) { s += bias[c]; s2 += bias[c]*bias[c]; }
      stats[80] = s * 0.015625f;
      stats[81] = s2 * 0.015625f;
    }
  }
}

// ---------------------------------------------------------------------------
// Main: per block, 64 batch rows.
//   phase 1: build psi (256 real amps/row, product state) -> fp16 in LDS
//   phase 2: C[64][512] = A[64][256] x Bt^T via mfma_f32_16x16x32_f16
//            wave w owns output cols: Re amps [w*64,w*64+64), Im +256
//   phase 3: probs; Z-expvals via in-lane WHT (bits 4-5) + cross-lane FWHT
//            (bits 0-3); cross-wave (bits 6-7) via LDS
//   phase 4-6: combine z, folded-LN stats, FC + LN + exact GELU
// Amp index a: b7b6 = wave, b5b4 = nfrag, b3..b0 = lane&15; wire w <-> bit 7-w.
// ---------------------------------------------------------------------------
__global__ __launch_bounds__(256) void qsb_main(
    const float* __restrict__ pca, const _Float16* __restrict__ Bt,
    const float* __restrict__ statsG,
    const float* __restrict__ Wm, const float* __restrict__ bias,
    const float* __restrict__ gamma, const float* __restrict__ beta,
    float* __restrict__ out, int B) {
  __shared__ __align__(16) _Float16 Alds[64 * 264];  // row stride 264 f16 = 528 B
  __shared__ float zpart[64 * 36];                   // [row][wave*8+slot], pad 36
  __shared__ float zrow[64 * 8];
  __shared__ float musig[64 * 2];
  __shared__ float Wl[512];
  __shared__ float biasL[64], gammaL[64], betaL[64];
  __shared__ float statsL[82];

  const int tid = threadIdx.x;
  const int wid = tid >> 6, lane = tid & 63;
  const int r0 = blockIdx.x * 64;

  // ---- phase 0: preloads ----
  for (int i = tid; i < 512; i += 256) Wl[i] = Wm[i];
  if (tid < 64) { biasL[tid] = bias[tid]; gammaL[tid] = gamma[tid]; betaL[tid] = beta[tid]; }
  if (tid >= 64 && tid < 64 + 82) statsL[tid - 64] = statsG[tid - 64];

  // ---- phase 1: A build ----
  {
    const int rl = tid & 63, q = tid >> 6;   // 4 threads per row, 64 amps each
    const int r = r0 + rl;
    float cv[8], sv[8];
    #pragma unroll
    for (int w = 0; w < 8; ++w) { cv[w] = 0.f; sv[w] = 0.f; }
    if (r < B) {
      #pragma unroll
      for (int w = 0; w < 8; ++w) {
        float x = pca[r*8 + w];
        float ang = 1.5707963267948966f / (1.f + expf(-x)); // (pi/2)*sigmoid
        cv[w] = cosf(ang); sv[w] = sinf(ang);
      }
    }
    float arr[64];
    arr[0] = ((q & 2) ? sv[0] : cv[0]) * ((q & 1) ? sv[1] : cv[1]);
    #pragma unroll
    for (int p = 0; p < 6; ++p) {          // bit p of m <-> wire 7-p
      const int w = 7 - p;
      const int sz = 1 << p;
      #pragma unroll
      for (int i = 0; i < (1 << p); ++i) {
        arr[i + sz] = arr[i] * sv[w];
        arr[i]      = arr[i] * cv[w];
      }
    }
    _Float16* dst = &Alds[rl*264 + q*64];
    #pragma unroll
    for (int i = 0; i < 8; ++i) {
      f16x8 v;
      #pragma unroll
      for (int j = 0; j < 8; ++j) v[j] = (_Float16)arr[i*8 + j];
      *(f16x8*)(dst + i*8) = v;
    }
  }
  __syncthreads();

  // ---- phase 2: GEMM ----
  f32x4 accRe[4][4], accIm[4][4];
  #pragma unroll
  for (int m = 0; m < 4; ++m)
    #pragma unroll
    for (int n = 0; n < 4; ++n) {
      accRe[m][n] = (f32x4){0.f, 0.f, 0.f, 0.f};
      accIm[m][n] = (f32x4){0.f, 0.f, 0.f, 0.f};
    }
  const int cfrag = lane & 15, kgrp = lane >> 4;
  const _Float16* BtW = Bt + (wid*64 + cfrag)*256 + kgrp*8;
  #pragma unroll 2
  for (int ks = 0; ks < 8; ++ks) {
    f16x8 af[4];
    #pragma unroll
    for (int m = 0; m < 4; ++m)
      af[m] = *(const f16x8*)&Alds[(m*16 + cfrag)*264 + ks*32 + kgrp*8];
    #pragma unroll
    for (int n = 0; n < 4; ++n) {
      f16x8 bre = *(const f16x8*)(BtW + n*16*256 + ks*32);
      f16x8 bim = *(const f16x8*)(BtW + 65536 + n*16*256 + ks*32);
      #pragma unroll
      for (int m = 0; m < 4; ++m) {
        accRe[m][n] = __builtin_amdgcn_mfma_f32_16x16x32_f16(af[m], bre, accRe[m][n], 0, 0, 0);
        accIm[m][n] = __builtin_amdgcn_mfma_f32_16x16x32_f16(af[m], bim, accIm[m][n], 0, 0, 0);
      }
    }
  }

  // ---- phase 3: probs + Z reduction ----
  #pragma unroll
  for (int m = 0; m < 4; ++m) {
    #pragma unroll
    for (int j = 0; j < 4; ++j) {
      float p0 = accRe[m][0][j]*accRe[m][0][j] + accIm[m][0][j]*accIm[m][0][j];
      float p1 = accRe[m][1][j]*accRe[m][1][j] + accIm[m][1][j]*accIm[m][1][j];
      float p2 = accRe[m][2][j]*accRe[m][2][j] + accIm[m][2][j]*accIm[m][2][j];
      float p3 = accRe[m][3][j]*accRe[m][3][j] + accIm[m][3][j]*accIm[m][3][j];
      float T  = (p0 + p1) + (p2 + p3);
      float U4 = (p0 - p1) + (p2 - p3);   // sign by b4 (nfrag bit0) -> wire 3
      float U5 = (p0 + p1) - (p2 + p3);   // sign by b5 (nfrag bit1) -> wire 2
      #pragma unroll
      for (int mm = 1; mm < 16; mm <<= 1) {
        U4 += shxor(U4, mm);
        U5 += shxor(U5, mm);
        float t2 = shxor(T, mm);
        T = (lane & mm) ? (t2 - T) : (T + t2);   // FWHT over col bits b0..b3
      }
      const int row = m*16 + (lane >> 4)*4 + j;
      float* zp = &zpart[row*36 + wid*8];
      const int c = lane & 15;
      if      (c == 0) { zp[0] = T; zp[1] = U5; zp[2] = U4; }
      else if (c == 8) zp[3] = T;   // sign b3 -> wire 4
      else if (c == 4) zp[4] = T;   // sign b2 -> wire 5
      else if (c == 2) zp[5] = T;   // sign b1 -> wire 6
      else if (c == 1) zp[6] = T;   // sign b0 -> wire 7
    }
  }
  __syncthreads();

  // ---- phase 4: combine across waves (b6,b7 = wave bits) ----
  {
    const int row = tid >> 2, pr = tid & 3;
    const float* zp = &zpart[row*36];
    float a0, a1;
    if (pr == 0) {
      float T0 = zp[0], T1 = zp[8], T2 = zp[16], T3 = zp[24];
      a0 = (T0 + T1) - (T2 + T3);   // wire 0: sign by wave>>1 (b7)
      a1 = (T0 + T2) - (T1 + T3);   // wire 1: sign by wave&1  (b6)
    } else {
      const int s0 = pr*2 - 1;      // pr=1->slots1,2(w2,w3) 2->3,4(w4,w5) 3->5,6(w6,w7)
      a0 = zp[s0]     + zp[8 + s0]     + zp[16 + s0]     + zp[24 + s0];
      a1 = zp[s0 + 1] + zp[8 + s0 + 1] + zp[16 + s0 + 1] + zp[24 + s0 + 1];
    }
    zrow[row*8 + pr*2]     = a0;
    zrow[row*8 + pr*2 + 1] = a1;
  }
  __syncthreads();

  // ---- phase 5: folded LN stats ----
  if (tid < 64) {
    float z[8];
    #pragma unroll
    for (int i = 0; i < 8; ++i) z[i] = zrow[tid*8 + i];
    float mu = statsL[80];
    #pragma unroll
    for (int i = 0; i < 8; ++i) mu += statsL[i] * z[i];
    float e2 = statsL[81];
    #pragma unroll
    for (int i = 0; i < 8; ++i) {
      float qi = statsL[8 + i];
      #pragma unroll
      for (int jj = 0; jj < 8; ++jj) qi += statsL[16 + i*8 + jj] * z[jj];
      e2 += z[i] * qi;
    }
    float var = e2 - mu*mu;
    musig[tid*2]     = mu;
    musig[tid*2 + 1] = rsqrtf(fmaxf(var, 0.f) + 1e-5f);
  }
  __syncthreads();

  // ---- phase 6: FC + LN + exact GELU ----
  #pragma unroll 4
  for (int rr = 0; rr < 16; ++rr) {
    const int row = wid*16 + rr;
    const int gr = r0 + row;
    float h = biasL[lane];
    #pragma unroll
    for (int i = 0; i < 8; ++i) h = fmaf(zrow[row*8 + i], Wl[i*64 + lane], h);
    float hn = (h - musig[row*2]) * musig[row*2 + 1] * gammaL[lane] + betaL[lane];
    float ge = 0.5f * hn * (1.f + erff(hn * 0.70710678118654752f));
    if (gr < B) out[gr*64 + lane] = ge;
  }
}

extern "C" void kernel_launch(void* const* d_in, const int* in_sizes, int n_in,
                              void* d_out, int out_size, void* d_ws, size_t ws_size,
                              hipStream_t stream) {
  const float* pca   = (const float*)d_in[0];
  const float* qw    = (const float*)d_in[1];
  const float* Wm    = (const float*)d_in[2];
  const float* bias  = (const float*)d_in[3];
  const float* gamma = (const float*)d_in[4];
  const float* beta  = (const float*)d_in[5];
  float* out = (float*)d_out;

  _Float16* Bt = (_Float16*)d_ws;                      // 512*256*2 = 256 KiB
  float* stats = (float*)((char*)d_ws + 512*256*2);    // 82 floats

  int B = in_sizes[0] / 8;

  hipLaunchKernelGGL(qsb_prep, dim3(257), dim3(64), 0, stream, qw, Wm, bias, Bt, stats);
  int blocks = (B + 63) / 64;
  hipLaunchKernelGGL(qsb_main, dim3(blocks), dim3(256), 0, stream,
                     pca, Bt, stats, Wm, bias, gamma, beta, out, B);
}

// Round 4
// 50.522 us; speedup vs baseline: 1.9205x; 1.3628x over previous
//
#include <hip/hip_runtime.h>
#include <math.h>

#define DEVFN __device__ __forceinline__

typedef __attribute__((ext_vector_type(8))) _Float16 f16x8;
typedef __attribute__((ext_vector_type(4))) float f32x4;

DEVFN float shxor(float v, int m) { return __shfl_xor(v, m, 64); }

// ---------------------------------------------------------------------------
// Gate machinery (verified R1/R3).
// State layout: amplitude index a (8 bits) = lane*4 + k; wire w <-> bit 7-w.
//   bits 7..2 -> lane bits 5..0 ; bits 1..0 -> k bits 1..0
// ---------------------------------------------------------------------------
template<int W>
DEVFN void rot_gate(int lane, float (&sr)[4], float (&si)[4], const float* u) {
  const float u00r=u[0], u00i=u[1], u01r=u[2], u01i=u[3];
  const float u10r=u[4], u10i=u[5], u11r=u[6], u11i=u[7];
  if constexpr (W <= 5) {
    constexpr int M = 1 << (5 - W);
    const bool hi = (lane & M) != 0;
    const float cmr = hi ? u11r : u00r, cmi = hi ? u11i : u00i;
    const float cor = hi ? u10r : u01r, coi = hi ? u10i : u01i;
    #pragma unroll
    for (int k = 0; k < 4; ++k) {
      float orr = shxor(sr[k], M);
      float oii = shxor(si[k], M);
      float nr = cmr*sr[k] - cmi*si[k] + cor*orr - coi*oii;
      float ni = cmr*si[k] + cmi*sr[k] + cor*oii + coi*orr;
      sr[k] = nr; si[k] = ni;
    }
  } else {
    constexpr int KB = (W == 6) ? 2 : 1;
    #pragma unroll
    for (int k0 = 0; k0 < 4; ++k0) {
      if ((k0 & KB) == 0) {
        const int k1 = k0 | KB;
        float ar = sr[k0], ai = si[k0];
        float br = sr[k1], bi = si[k1];
        sr[k0] = u00r*ar - u00i*ai + u01r*br - u01i*bi;
        si[k0] = u00r*ai + u00i*ar + u01r*bi + u01i*br;
        sr[k1] = u10r*ar - u10i*ai + u11r*br - u11i*bi;
        si[k1] = u10r*ai + u10i*ar + u11r*bi + u11i*br;
      }
    }
  }
}

template<int C, int T>
DEVFN void cnot_gate(int lane, float (&sr)[4], float (&si)[4]) {
  constexpr int PC = 7 - C, PT = 7 - T;
  if constexpr (PT >= 2) {
    constexpr int M = 1 << (PT - 2);
    #pragma unroll
    for (int k = 0; k < 4; ++k) {
      float orr = shxor(sr[k], M);
      float oii = shxor(si[k], M);
      bool ctrl;
      if constexpr (PC >= 2) ctrl = ((lane >> (PC - 2)) & 1) != 0;
      else                   ctrl = ((k >> PC) & 1) != 0;
      if (ctrl) { sr[k] = orr; si[k] = oii; }
    }
  } else {
    float tr[4], ti[4];
    #pragma unroll
    for (int k = 0; k < 4; ++k) { tr[k] = sr[k]; ti[k] = si[k]; }
    #pragma unroll
    for (int k = 0; k < 4; ++k) {
      bool ctrl;
      if constexpr (PC >= 2) ctrl = ((lane >> (PC - 2)) & 1) != 0;
      else                   ctrl = ((k >> PC) & 1) != 0;
      if (ctrl) { sr[k] = tr[k ^ (1 << PT)]; si[k] = ti[k ^ (1 << PT)]; }
    }
  }
}

// ---------------------------------------------------------------------------
// Prep: blocks 0..255 simulate basis state e_col -> one column of the circuit
// unitary. Bt layout (f16, [512 rows][256 cols], row = n):
//   amp a: chunk = a>>5, j = a&31;  Re -> n = chunk*64 + j ; Im -> n + 32.
// Block 256: folded LayerNorm/FC stats:
//   stats[0..7]=colmean(W), [8..15]=2*W.b/64, [16..79]=W.Wt/64, [80]=mean(b),
//   [81]=mean(b^2)
// ---------------------------------------------------------------------------
__global__ __launch_bounds__(64) void qsb_prep(
    const float* __restrict__ qw, const float* __restrict__ Wm,
    const float* __restrict__ bias,
    _Float16* __restrict__ Bt, float* __restrict__ stats) {
  __shared__ float uL[16 * 8];
  int bid = blockIdx.x;
  int lane = threadIdx.x;
  if (bid < 256) {
    // hoist gate-matrix trig: thread g<16 computes gate g's 2x2 U into LDS
    if (lane < 16) {
      int l = lane >> 3, i = lane & 7;
      float phi = qw[l*24 + i*3 + 0];
      float th  = qw[l*24 + i*3 + 1];
      float om  = qw[l*24 + i*3 + 2];
      float cth = cosf(0.5f*th), sth = sinf(0.5f*th);
      float ap = 0.5f*(phi+om), am = 0.5f*(phi-om);
      float cap = cosf(ap), sap = sinf(ap);
      float cam = cosf(am), sam = sinf(am);
      float* u = &uL[lane*8];
      u[0] =  cap*cth; u[1] = -sap*cth;   // U00 = ep*c
      u[2] = -cam*sth; u[3] = -sam*sth;   // U01 = -conj(em)*s
      u[4] =  cam*sth; u[5] = -sam*sth;   // U10 = em*s
      u[6] =  cap*cth; u[7] =  sap*cth;   // U11 = conj(ep)*c
    }
    __syncthreads();
    int col = bid;
    float sr[4], si[4];
    #pragma unroll
    for (int k = 0; k < 4; ++k) { sr[k] = (lane*4 + k == col) ? 1.f : 0.f; si[k] = 0.f; }
    // layer 0
    rot_gate<0>(lane, sr, si, &uL[0*8]);
    rot_gate<1>(lane, sr, si, &uL[1*8]);
    rot_gate<2>(lane, sr, si, &uL[2*8]);
    rot_gate<3>(lane, sr, si, &uL[3*8]);
    rot_gate<4>(lane, sr, si, &uL[4*8]);
    rot_gate<5>(lane, sr, si, &uL[5*8]);
    rot_gate<6>(lane, sr, si, &uL[6*8]);
    rot_gate<7>(lane, sr, si, &uL[7*8]);
    cnot_gate<0,1>(lane, sr, si);
    cnot_gate<1,2>(lane, sr, si);
    cnot_gate<2,3>(lane, sr, si);
    cnot_gate<3,4>(lane, sr, si);
    cnot_gate<4,5>(lane, sr, si);
    cnot_gate<5,6>(lane, sr, si);
    cnot_gate<6,7>(lane, sr, si);
    cnot_gate<7,0>(lane, sr, si);
    // layer 1 (ring r=2)
    rot_gate<0>(lane, sr, si, &uL[(8+0)*8]);
    rot_gate<1>(lane, sr, si, &uL[(8+1)*8]);
    rot_gate<2>(lane, sr, si, &uL[(8+2)*8]);
    rot_gate<3>(lane, sr, si, &uL[(8+3)*8]);
    rot_gate<4>(lane, sr, si, &uL[(8+4)*8]);
    rot_gate<5>(lane, sr, si, &uL[(8+5)*8]);
    rot_gate<6>(lane, sr, si, &uL[(8+6)*8]);
    rot_gate<7>(lane, sr, si, &uL[(8+7)*8]);
    cnot_gate<0,2>(lane, sr, si);
    cnot_gate<1,3>(lane, sr, si);
    cnot_gate<2,4>(lane, sr, si);
    cnot_gate<3,5>(lane, sr, si);
    cnot_gate<4,6>(lane, sr, si);
    cnot_gate<5,7>(lane, sr, si);
    cnot_gate<6,0>(lane, sr, si);
    cnot_gate<7,1>(lane, sr, si);
    #pragma unroll
    for (int k = 0; k < 4; ++k) {
      int a = lane*4 + k;
      int nRe = (a >> 5)*64 + (a & 31);
      Bt[nRe*256 + col]        = (_Float16)sr[k];
      Bt[(nRe + 32)*256 + col] = (_Float16)si[k];
    }
  } else {
    int t = lane;
    {
      int i = t >> 3, j = t & 7;
      float s = 0.f;
      for (int c = 0; c < 64; ++c) s += Wm[i*64 + c] * Wm[j*64 + c];
      stats[16 + t] = s * 0.015625f;
    }
    if (t < 8) {
      float s = 0.f, sb = 0.f;
      for (int c = 0; c < 64; ++c) { float w = Wm[t*64 + c]; s += w; sb += w * bias[c]; }
      stats[t]     = s * 0.015625f;
      stats[8 + t] = 2.f * sb * 0.015625f;
    }
    if (t == 0) {
      float s = 0.f, s2 = 0.f;
      for (int c = 0; c < 64; ++c) { s += bias[c]; s2 += bias[c]*bias[c]; }
      stats[80] = s * 0.015625f;
      stats[81] = s2 * 0.015625f;
    }
  }
}

// ---------------------------------------------------------------------------
// Main: 32 rows per block, 256 threads (4 waves), 1024 blocks.
// A LDS layout (k-major tiled, conflict-free MFMA reads):
//   element (row,k): idx = ks*1024 + m*512 + kg*128 + cf*8 + e
//   where ks=k>>5, kg=(k>>3)&3, e=k&7, m=row>>4, cf=row&15.
// Wave w owns chunks {2w, 2w+1}; chunk ch covers amps a in [ch*32, ch*32+32):
//   Bt rows ch*64 + q*16 + cf (q<2: Re nf=q; q>=2: Im nf=q-2).
// Amp bits: b7b6b5 = chunk, b4 = nf, b3..b0 = cfrag; wire w <-> bit 7-w.
// ---------------------------------------------------------------------------
__global__ __launch_bounds__(256, 4) void qsb_main(
    const float* __restrict__ pca, const _Float16* __restrict__ Bt,
    const float* __restrict__ statsG,
    const float* __restrict__ Wm, const float* __restrict__ bias,
    const float* __restrict__ gamma, const float* __restrict__ beta,
    float* __restrict__ out, int B) {
  __shared__ __align__(16) _Float16 A3[8192];   // 32 rows x 256 k, tiled
  __shared__ float zpart[32 * 72];              // [row][chunk*9 + slot]
  __shared__ float zrow[32 * 8];
  __shared__ float musig[32 * 2];
  __shared__ float Wl[512];
  __shared__ float biasL[64], gammaL[64], betaL[64];
  __shared__ float statsL[82];

  const int tid = threadIdx.x;
  const int wid = tid >> 6, lane = tid & 63;
  const int r0 = blockIdx.x * 32;

  // ---- phase 0: preloads ----
  for (int i = tid; i < 512; i += 256) Wl[i] = Wm[i];
  if (tid < 64) { biasL[tid] = bias[tid]; gammaL[tid] = gamma[tid]; betaL[tid] = beta[tid]; }
  if (tid >= 64 && tid < 64 + 82) statsL[tid - 64] = statsG[tid - 64];

  // ---- phase 1: A build (8 threads/row, 32 amps each) ----
  {
    const int rl = tid >> 3, tq = tid & 7;   // row-local, amp-block
    const int r = r0 + rl;
    float cv[8], sv[8];
    #pragma unroll
    for (int w = 0; w < 8; ++w) { cv[w] = 0.f; sv[w] = 0.f; }
    if (r < B) {
      #pragma unroll
      for (int w = 0; w < 8; ++w) {
        float x = pca[r*8 + w];
        float ang = 1.5707963267948966f / (1.f + expf(-x)); // (pi/2)*sigmoid
        cv[w] = cosf(ang); sv[w] = sinf(ang);
      }
    }
    // high bits b7b6b5 = tq -> wires 0,1,2
    float base = ((tq & 4) ? sv[0] : cv[0]) * ((tq & 2) ? sv[1] : cv[1])
               * ((tq & 1) ? sv[2] : cv[2]);
    float arr[32];
    arr[0] = base;
    #pragma unroll
    for (int p = 0; p < 5; ++p) {            // bit p of i <-> wire 7-p
      const int w = 7 - p;
      const int sz = 1 << p;
      #pragma unroll
      for (int i = 0; i < (1 << p); ++i) {
        arr[i + sz] = arr[i] * sv[w];
        arr[i]      = arr[i] * cv[w];
      }
    }
    // write: k = tq*32 + ib*8 + e  ->  idx = tq*1024 + m*512 + ib*128 + cf*8 + e
    _Float16* dst = &A3[tq*1024 + (rl >> 4)*512 + (rl & 15)*8];
    #pragma unroll
    for (int ib = 0; ib < 4; ++ib) {
      f16x8 v;
      #pragma unroll
      for (int j = 0; j < 8; ++j) v[j] = (_Float16)arr[ib*8 + j];
      *(f16x8*)(dst + ib*128) = v;
    }
  }
  __syncthreads();

  // ---- phase 2+3: per chunk: GEMM then probs/FWHT partials ----
  const int cfrag = lane & 15, kgrp = lane >> 4;
  #pragma unroll
  for (int c = 0; c < 2; ++c) {
    f32x4 acc[2][4];
    #pragma unroll
    for (int m = 0; m < 2; ++m)
      #pragma unroll
      for (int q = 0; q < 4; ++q) acc[m][q] = (f32x4){0.f, 0.f, 0.f, 0.f};

    const _Float16* Bc = Bt + ((wid*2 + c)*64 + cfrag)*256 + kgrp*8;
    #pragma unroll 2
    for (int ks = 0; ks < 8; ++ks) {
      f16x8 af0 = *(const f16x8*)&A3[ks*1024 +       kgrp*128 + cfrag*8];
      f16x8 af1 = *(const f16x8*)&A3[ks*1024 + 512 + kgrp*128 + cfrag*8];
      #pragma unroll
      for (int q = 0; q < 4; ++q) {
        f16x8 bq = *(const f16x8*)(Bc + q*4096 + ks*32);
        acc[0][q] = __builtin_amdgcn_mfma_f32_16x16x32_f16(af0, bq, acc[0][q], 0, 0, 0);
        acc[1][q] = __builtin_amdgcn_mfma_f32_16x16x32_f16(af1, bq, acc[1][q], 0, 0, 0);
      }
    }

    const int ch = wid*2 + c;
    #pragma unroll
    for (int m = 0; m < 2; ++m) {
      #pragma unroll
      for (int j = 0; j < 4; ++j) {
        float re0 = acc[m][0][j], re1 = acc[m][1][j];
        float im0 = acc[m][2][j], im1 = acc[m][3][j];
        float p0 = re0*re0 + im0*im0;     // nf=0 (b4=0)
        float p1 = re1*re1 + im1*im1;     // nf=1 (b4=1)
        float T = p0 + p1, S4 = p0 - p1;
        #pragma unroll
        for (int mm = 1; mm < 16; mm <<= 1) {
          S4 += shxor(S4, mm);
          float t2 = shxor(T, mm);
          T = (lane & mm) ? (t2 - T) : (T + t2);   // FWHT over b0..b3
        }
        const int row = m*16 + kgrp*4 + j;
        float* zp = &zpart[row*72 + ch*9];
        const int cc = lane & 15;
        if      (cc == 0) { zp[0] = T; zp[1] = S4; }  // total, sign-b4 (wire3)
        else if (cc == 8) zp[2] = T;   // sign b3 -> wire 4
        else if (cc == 4) zp[3] = T;   // sign b2 -> wire 5
        else if (cc == 2) zp[4] = T;   // sign b1 -> wire 6
        else if (cc == 1) zp[5] = T;   // sign b0 -> wire 7
      }
    }
  }
  __syncthreads();

  // ---- phase 4: combine across 8 chunks (b7b6b5) ----
  {
    const int row = tid >> 3, wire = tid & 7;
    const float* zp = &zpart[row*72];
    const int slot = (wire < 3) ? 0 : (wire - 2);
    const int sm = (wire == 0) ? 4 : (wire == 1) ? 2 : (wire == 2) ? 1 : 0;
    float a = 0.f;
    #pragma unroll
    for (int ch = 0; ch < 8; ++ch) {
      float v = zp[ch*9 + slot];
      a += (ch & sm) ? -v : v;
    }
    zrow[row*8 + wire] = a;
  }
  __syncthreads();

  // ---- phase 5: folded LN stats (8 threads/row) ----
  {
    const int row = tid >> 3, ii = tid & 7;
    float zj[8];
    #pragma unroll
    for (int j = 0; j < 8; ++j) zj[j] = zrow[row*8 + j];
    float qi = statsL[8 + ii];
    #pragma unroll
    for (int j = 0; j < 8; ++j) qi += statsL[16 + ii*8 + j] * zj[j];
    float e2p = zj[ii] * qi;
    float mup = statsL[ii] * zj[ii];
    e2p += shxor(e2p, 1); e2p += shxor(e2p, 2); e2p += shxor(e2p, 4);
    mup += shxor(mup, 1); mup += shxor(mup, 2); mup += shxor(mup, 4);
    if (ii == 0) {
      float mu = mup + statsL[80];
      float e2 = e2p + statsL[81];
      float var = e2 - mu*mu;
      musig[row*2]     = mu;
      musig[row*2 + 1] = rsqrtf(fmaxf(var, 0.f) + 1e-5f);
    }
  }
  __syncthreads();

  // ---- phase 6: FC + LN + exact GELU (8 rows per wave) ----
  #pragma unroll
  for (int rr = 0; rr < 8; ++rr) {
    const int row = wid*8 + rr;
    const int gr = r0 + row;
    float h = biasL[lane];
    #pragma unroll
    for (int i = 0; i < 8; ++i) h = fmaf(zrow[row*8 + i], Wl[i*64 + lane], h);
    float hn = (h - musig[row*2]) * musig[row*2 + 1] * gammaL[lane] + betaL[lane];
    float ge = 0.5f * hn * (1.f + erff(hn * 0.70710678118654752f));
    if (gr < B) out[gr*64 + lane] = ge;
  }
}

extern "C" void kernel_launch(void* const* d_in, const int* in_sizes, int n_in,
                              void* d_out, int out_size, void* d_ws, size_t ws_size,
                              hipStream_t stream) {
  const float* pca   = (const float*)d_in[0];
  const float* qw    = (const float*)d_in[1];
  const float* Wm    = (const float*)d_in[2];
  const float* bias  = (const float*)d_in[3];
  const float* gamma = (const float*)d_in[4];
  const float* beta  = (const float*)d_in[5];
  float* out = (float*)d_out;

  _Float16* Bt = (_Float16*)d_ws;                      // 512*256*2 = 256 KiB
  float* stats = (float*)((char*)d_ws + 512*256*2);    // 82 floats

  int B = in_sizes[0] / 8;

  hipLaunchKernelGGL(qsb_prep, dim3(257), dim3(64), 0, stream, qw, Wm, bias, Bt, stats);
  int blocks = (B + 31) / 32;
  hipLaunchKernelGGL(qsb_main, dim3(blocks), dim3(256), 0, stream,
                     pca, Bt, stats, Wm, bias, gamma, beta, out, B);
}

// Round 5
// 31.417 us; speedup vs baseline: 3.0885x; 1.6081x over previous
//
#include <hip/hip_runtime.h>
#include <math.h>

#define DEVFN __device__ __forceinline__

typedef __attribute__((ext_vector_type(8))) _Float16 f16x8;
typedef __attribute__((ext_vector_type(4))) float f32x4;

DEVFN float shxor(float v, int m) { return __shfl_xor(v, m, 64); }

// ---------------------------------------------------------------------------
// Gate machinery (verified R1/R3/R4).
// State layout: amplitude index a (8 bits) = lane*4 + k; wire w <-> bit 7-w.
//   bits 7..2 -> lane bits 5..0 ; bits 1..0 -> k bits 1..0
// ---------------------------------------------------------------------------
template<int W>
DEVFN void rot_gate(int lane, float (&sr)[4], float (&si)[4], const float* u) {
  const float u00r=u[0], u00i=u[1], u01r=u[2], u01i=u[3];
  const float u10r=u[4], u10i=u[5], u11r=u[6], u11i=u[7];
  if constexpr (W <= 5) {
    constexpr int M = 1 << (5 - W);
    const bool hi = (lane & M) != 0;
    const float cmr = hi ? u11r : u00r, cmi = hi ? u11i : u00i;
    const float cor = hi ? u10r : u01r, coi = hi ? u10i : u01i;
    #pragma unroll
    for (int k = 0; k < 4; ++k) {
      float orr = shxor(sr[k], M);
      float oii = shxor(si[k], M);
      float nr = cmr*sr[k] - cmi*si[k] + cor*orr - coi*oii;
      float ni = cmr*si[k] + cmi*sr[k] + cor*oii + coi*orr;
      sr[k] = nr; si[k] = ni;
    }
  } else {
    constexpr int KB = (W == 6) ? 2 : 1;
    #pragma unroll
    for (int k0 = 0; k0 < 4; ++k0) {
      if ((k0 & KB) == 0) {
        const int k1 = k0 | KB;
        float ar = sr[k0], ai = si[k0];
        float br = sr[k1], bi = si[k1];
        sr[k0] = u00r*ar - u00i*ai + u01r*br - u01i*bi;
        si[k0] = u00r*ai + u00i*ar + u01r*bi + u01i*br;
        sr[k1] = u10r*ar - u10i*ai + u11r*br - u11i*bi;
        si[k1] = u10r*ai + u10i*ar + u11r*bi + u11i*br;
      }
    }
  }
}

template<int C, int T>
DEVFN void cnot_gate(int lane, float (&sr)[4], float (&si)[4]) {
  constexpr int PC = 7 - C, PT = 7 - T;
  if constexpr (PT >= 2) {
    constexpr int M = 1 << (PT - 2);
    #pragma unroll
    for (int k = 0; k < 4; ++k) {
      float orr = shxor(sr[k], M);
      float oii = shxor(si[k], M);
      bool ctrl;
      if constexpr (PC >= 2) ctrl = ((lane >> (PC - 2)) & 1) != 0;
      else                   ctrl = ((k >> PC) & 1) != 0;
      if (ctrl) { sr[k] = orr; si[k] = oii; }
    }
  } else {
    float tr[4], ti[4];
    #pragma unroll
    for (int k = 0; k < 4; ++k) { tr[k] = sr[k]; ti[k] = si[k]; }
    #pragma unroll
    for (int k = 0; k < 4; ++k) {
      bool ctrl;
      if constexpr (PC >= 2) ctrl = ((lane >> (PC - 2)) & 1) != 0;
      else                   ctrl = ((k >> PC) & 1) != 0;
      if (ctrl) { sr[k] = tr[k ^ (1 << PT)]; si[k] = ti[k ^ (1 << PT)]; }
    }
  }
}

// ---------------------------------------------------------------------------
// Prep: blocks 0..255 simulate basis state e_col (col = GEMM K index) and
// scatter into the per-wave MFMA fragment layout:
//   Bfrag[((ch*4 + q)*8 + ks)*512 + (kg*16 + cf)*8 + e]  (f16)
//   where amp a: ch=a>>5, nf=(a>>4)&1, cf=a&15; q = nf (Re) / 2+nf (Im);
//   col j: ks=j>>5, kg=(j>>3)&3, e=j&7.
// Every main-kernel B load is then one contiguous 1 KB wave read.
// Block 256: folded LayerNorm/FC stats (as R4).
// ---------------------------------------------------------------------------
__global__ __launch_bounds__(64) void qsb_prep(
    const float* __restrict__ qw, const float* __restrict__ Wm,
    const float* __restrict__ bias,
    _Float16* __restrict__ Bfrag, float* __restrict__ stats) {
  __shared__ float uL[16 * 8];
  int bid = blockIdx.x;
  int lane = threadIdx.x;
  if (bid < 256) {
    if (lane < 16) {
      int l = lane >> 3, i = lane & 7;
      float phi = qw[l*24 + i*3 + 0];
      float th  = qw[l*24 + i*3 + 1];
      float om  = qw[l*24 + i*3 + 2];
      float cth = cosf(0.5f*th), sth = sinf(0.5f*th);
      float ap = 0.5f*(phi+om), am = 0.5f*(phi-om);
      float cap = cosf(ap), sap = sinf(ap);
      float cam = cosf(am), sam = sinf(am);
      float* u = &uL[lane*8];
      u[0] =  cap*cth; u[1] = -sap*cth;
      u[2] = -cam*sth; u[3] = -sam*sth;
      u[4] =  cam*sth; u[5] = -sam*sth;
      u[6] =  cap*cth; u[7] =  sap*cth;
    }
    __syncthreads();
    int col = bid;
    float sr[4], si[4];
    #pragma unroll
    for (int k = 0; k < 4; ++k) { sr[k] = (lane*4 + k == col) ? 1.f : 0.f; si[k] = 0.f; }
    rot_gate<0>(lane, sr, si, &uL[0*8]);
    rot_gate<1>(lane, sr, si, &uL[1*8]);
    rot_gate<2>(lane, sr, si, &uL[2*8]);
    rot_gate<3>(lane, sr, si, &uL[3*8]);
    rot_gate<4>(lane, sr, si, &uL[4*8]);
    rot_gate<5>(lane, sr, si, &uL[5*8]);
    rot_gate<6>(lane, sr, si, &uL[6*8]);
    rot_gate<7>(lane, sr, si, &uL[7*8]);
    cnot_gate<0,1>(lane, sr, si);
    cnot_gate<1,2>(lane, sr, si);
    cnot_gate<2,3>(lane, sr, si);
    cnot_gate<3,4>(lane, sr, si);
    cnot_gate<4,5>(lane, sr, si);
    cnot_gate<5,6>(lane, sr, si);
    cnot_gate<6,7>(lane, sr, si);
    cnot_gate<7,0>(lane, sr, si);
    rot_gate<0>(lane, sr, si, &uL[(8+0)*8]);
    rot_gate<1>(lane, sr, si, &uL[(8+1)*8]);
    rot_gate<2>(lane, sr, si, &uL[(8+2)*8]);
    rot_gate<3>(lane, sr, si, &uL[(8+3)*8]);
    rot_gate<4>(lane, sr, si, &uL[(8+4)*8]);
    rot_gate<5>(lane, sr, si, &uL[(8+5)*8]);
    rot_gate<6>(lane, sr, si, &uL[(8+6)*8]);
    rot_gate<7>(lane, sr, si, &uL[(8+7)*8]);
    cnot_gate<0,2>(lane, sr, si);
    cnot_gate<1,3>(lane, sr, si);
    cnot_gate<2,4>(lane, sr, si);
    cnot_gate<3,5>(lane, sr, si);
    cnot_gate<4,6>(lane, sr, si);
    cnot_gate<5,7>(lane, sr, si);
    cnot_gate<6,0>(lane, sr, si);
    cnot_gate<7,1>(lane, sr, si);
    const int ks = col >> 5, kg = (col >> 3) & 3, e = col & 7;
    #pragma unroll
    for (int k = 0; k < 4; ++k) {
      int a = lane*4 + k;
      int ch = a >> 5, nf = (a >> 4) & 1, cf = a & 15;
      int pos = (kg*16 + cf)*8 + e;
      Bfrag[((ch*4 + nf    )*8 + ks)*512 + pos] = (_Float16)sr[k];
      Bfrag[((ch*4 + 2 + nf)*8 + ks)*512 + pos] = (_Float16)si[k];
    }
  } else {
    int t = lane;
    {
      int i = t >> 3, j = t & 7;
      float s = 0.f;
      for (int c = 0; c < 64; ++c) s += Wm[i*64 + c] * Wm[j*64 + c];
      stats[16 + t] = s * 0.015625f;
    }
    if (t < 8) {
      float s = 0.f, sb = 0.f;
      for (int c = 0; c < 64; ++c) { float w = Wm[t*64 + c]; s += w; sb += w * bias[c]; }
      stats[t]     = s * 0.015625f;
      stats[8 + t] = 2.f * sb * 0.015625f;
    }
    if (t == 0) {
      float s = 0.f, s2 = 0.f;
      for (int c = 0; c < 64; ++c) { s += bias[c]; s2 += bias[c]*bias[c]; }
      stats[80] = s * 0.015625f;
      stats[81] = s2 * 0.015625f;
    }
  }
}

// ---------------------------------------------------------------------------
// Main: 64 rows/block, 512 threads (8 waves), grid = B/64 = 512 blocks.
// Wave wid owns chunk ch = wid (amps [ch*32, ch*32+32)) for ALL 64 rows:
//   M=64 (4 m-tiles), N=64 (q=0..3: Re nf0, Re nf1, Im nf0, Im nf1), K=256.
// A3 LDS layout (XOR-swizzled, conflict-free b128 read AND write):
//   element (row,k): ((ks*4 + m)*16 + cf)*32 + (kg ^ (ks&3))*8 + e
//   ks=k>>5, kg=(k>>3)&3, e=k&7, m=row>>4, cf=row&15.
// Amp bits: b7b6b5 = chunk, b4 = nf, b3..b0 = cf; wire w <-> bit 7-w.
// ---------------------------------------------------------------------------
__global__ __launch_bounds__(512, 4) void qsb_main(
    const float* __restrict__ pca, const _Float16* __restrict__ Bfrag,
    const float* __restrict__ statsG,
    const float* __restrict__ Wm, const float* __restrict__ bias,
    const float* __restrict__ gamma, const float* __restrict__ beta,
    float* __restrict__ out, int B) {
  __shared__ __align__(16) _Float16 A3[16384];   // 64 rows x 256 k, 32 KB
  __shared__ float zpart[64 * 49];               // [row][ch*6 + slot]
  __shared__ float zrow[64 * 8];
  __shared__ float musig[64 * 2];
  __shared__ float Wl[512];
  __shared__ float biasL[64], gammaL[64], betaL[64];
  __shared__ float statsL[82];

  const int tid = threadIdx.x;
  const int wid = tid >> 6, lane = tid & 63;
  const int r0 = blockIdx.x * 64;

  // ---- phase 0: preloads ----
  Wl[tid] = Wm[tid];
  if (tid < 64) { biasL[tid] = bias[tid]; gammaL[tid] = gamma[tid]; betaL[tid] = beta[tid]; }
  if (tid >= 64 && tid < 146) statsL[tid - 64] = statsG[tid - 64];

  // ---- phase 1: A build (8 threads/row, 32 k-values each), fast-math trig ----
  {
    const int rl = tid >> 3, tq = tid & 7;
    const int r = r0 + rl;
    float cv[8], sv[8];
    #pragma unroll
    for (int w = 0; w < 8; ++w) { cv[w] = 1.f; sv[w] = 0.f; }
    if (r < B) {
      #pragma unroll
      for (int w = 0; w < 8; ++w) {
        float x = pca[r*8 + w];
        float sg = __builtin_amdgcn_rcpf(1.f + __expf(-x));   // sigmoid
        float ang = 1.5707963267948966f * sg;                 // (pi/2)*sigmoid
        cv[w] = __cosf(ang); sv[w] = __sinf(ang);
      }
    }
    // k high bits b7b6b5 = tq -> wires 0,1,2
    float base = ((tq & 4) ? sv[0] : cv[0]) * ((tq & 2) ? sv[1] : cv[1])
               * ((tq & 1) ? sv[2] : cv[2]);
    float arr[32];
    arr[0] = base;
    #pragma unroll
    for (int p = 0; p < 5; ++p) {            // bit p of i <-> wire 7-p
      const int w = 7 - p;
      const int sz = 1 << p;
      #pragma unroll
      for (int i = 0; i < (1 << p); ++i) {
        arr[i + sz] = arr[i] * sv[w];
        arr[i]      = arr[i] * cv[w];
      }
    }
    // write k-block ib (k = tq*32+ib*8+e) at swizzled slot ib^(tq&3)
    _Float16* dstBase = &A3[((tq*4 + (rl >> 4))*16 + (rl & 15))*32];
    #pragma unroll
    for (int ib = 0; ib < 4; ++ib) {
      f16x8 v;
      #pragma unroll
      for (int j = 0; j < 8; ++j) v[j] = (_Float16)arr[ib*8 + j];
      *(f16x8*)(dstBase + (ib ^ (tq & 3))*8) = v;
    }
  }
  __syncthreads();

  // ---- phase 2: GEMM, wave = chunk wid, all 64 rows ----
  const int cfrag = lane & 15, kgrp = lane >> 4;
  f32x4 acc[4][4];
  #pragma unroll
  for (int m = 0; m < 4; ++m)
    #pragma unroll
    for (int q = 0; q < 4; ++q) acc[m][q] = (f32x4){0.f, 0.f, 0.f, 0.f};

  const _Float16* Bw = Bfrag + (wid*4)*8*512 + lane*8;
  #pragma unroll 2
  for (int ks = 0; ks < 8; ++ks) {
    const int slot = (kgrp ^ (ks & 3))*8;
    f16x8 af[4];
    #pragma unroll
    for (int m = 0; m < 4; ++m)
      af[m] = *(const f16x8*)&A3[((ks*4 + m)*16 + cfrag)*32 + slot];
    #pragma unroll
    for (int q = 0; q < 4; ++q) {
      f16x8 bq = *(const f16x8*)(Bw + (q*8 + ks)*512);
      #pragma unroll
      for (int m = 0; m < 4; ++m)
        acc[m][q] = __builtin_amdgcn_mfma_f32_16x16x32_f16(af[m], bq, acc[m][q], 0, 0, 0);
    }
  }

  // ---- phase 3: probs + FWHT partials (per wave, chunk = wid) ----
  #pragma unroll
  for (int m = 0; m < 4; ++m) {
    #pragma unroll
    for (int j = 0; j < 4; ++j) {
      float re0 = acc[m][0][j], re1 = acc[m][1][j];
      float im0 = acc[m][2][j], im1 = acc[m][3][j];
      float p0 = re0*re0 + im0*im0;     // nf=0 (b4=0)
      float p1 = re1*re1 + im1*im1;     // nf=1 (b4=1)
      float T = p0 + p1, S4 = p0 - p1;
      #pragma unroll
      for (int mm = 1; mm < 16; mm <<= 1) {
        S4 += shxor(S4, mm);
        float t2 = shxor(T, mm);
        T = (lane & mm) ? (t2 - T) : (T + t2);   // FWHT over b0..b3
      }
      const int row = m*16 + kgrp*4 + j;
      float* zp = &zpart[row*49 + wid*6];
      const int cc = lane & 15;
      if      (cc == 0) { zp[0] = T; zp[1] = S4; }  // total, sign-b4 (wire3)
      else if (cc == 8) zp[2] = T;   // sign b3 -> wire 4
      else if (cc == 4) zp[3] = T;   // sign b2 -> wire 5
      else if (cc == 2) zp[4] = T;   // sign b1 -> wire 6
      else if (cc == 1) zp[5] = T;   // sign b0 -> wire 7
    }
  }
  __syncthreads();

  // ---- phase 4: combine across 8 chunks (b7b6b5 -> wires 0,1,2 signs) ----
  {
    const int row = tid >> 3, wire = tid & 7;
    const float* zp = &zpart[row*49];
    const int slot = (wire < 3) ? 0 : (wire - 2);
    const int sm = (wire == 0) ? 4 : (wire == 1) ? 2 : (wire == 2) ? 1 : 0;
    float a = 0.f;
    #pragma unroll
    for (int ch = 0; ch < 8; ++ch) {
      float v = zp[ch*6 + slot];
      a += (ch & sm) ? -v : v;
    }
    zrow[row*8 + wire] = a;
  }
  __syncthreads();

  // ---- phase 5: folded LN stats (8 threads/row) ----
  {
    const int row = tid >> 3, ii = tid & 7;
    float zj[8];
    #pragma unroll
    for (int j = 0; j < 8; ++j) zj[j] = zrow[row*8 + j];
    float qi = statsL[8 + ii];
    #pragma unroll
    for (int j = 0; j < 8; ++j) qi += statsL[16 + ii*8 + j] * zj[j];
    float e2p = zj[ii] * qi;
    float mup = statsL[ii] * zj[ii];
    e2p += shxor(e2p, 1); e2p += shxor(e2p, 2); e2p += shxor(e2p, 4);
    mup += shxor(mup, 1); mup += shxor(mup, 2); mup += shxor(mup, 4);
    if (ii == 0) {
      float mu = mup + statsL[80];
      float e2 = e2p + statsL[81];
      float var = e2 - mu*mu;
      musig[row*2]     = mu;
      musig[row*2 + 1] = rsqrtf(fmaxf(var, 0.f) + 1e-5f);
    }
  }
  __syncthreads();

  // ---- phase 6: FC + LN + exact GELU (8 rows per wave) ----
  #pragma unroll
  for (int rr = 0; rr < 8; ++rr) {
    const int row = wid*8 + rr;
    const int gr = r0 + row;
    float h = biasL[lane];
    #pragma unroll
    for (int i = 0; i < 8; ++i) h = fmaf(zrow[row*8 + i], Wl[i*64 + lane], h);
    float hn = (h - musig[row*2]) * musig[row*2 + 1] * gammaL[lane] + betaL[lane];
    float ge = 0.5f * hn * (1.f + erff(hn * 0.70710678118654752f));
    if (gr < B) out[gr*64 + lane] = ge;
  }
}

extern "C" void kernel_launch(void* const* d_in, const int* in_sizes, int n_in,
                              void* d_out, int out_size, void* d_ws, size_t ws_size,
                              hipStream_t stream) {
  const float* pca   = (const float*)d_in[0];
  const float* qw    = (const float*)d_in[1];
  const float* Wm    = (const float*)d_in[2];
  const float* bias  = (const float*)d_in[3];
  const float* gamma = (const float*)d_in[4];
  const float* beta  = (const float*)d_in[5];
  float* out = (float*)d_out;

  _Float16* Bfrag = (_Float16*)d_ws;                   // 512*256*2 = 256 KiB
  float* stats = (float*)((char*)d_ws + 512*256*2);    // 82 floats

  int B = in_sizes[0] / 8;

  hipLaunchKernelGGL(qsb_prep, dim3(257), dim3(64), 0, stream, qw, Wm, bias, Bfrag, stats);
  int blocks = (B + 63) / 64;
  hipLaunchKernelGGL(qsb_main, dim3(blocks), dim3(512), 0, stream,
                     pca, Bfrag, stats, Wm, bias, gamma, beta, out, B);
}

// Round 7
// 28.579 us; speedup vs baseline: 3.3952x; 1.0993x over previous
//
#include <hip/hip_runtime.h>
#include <math.h>

#define DEVFN __device__ __forceinline__

typedef __attribute__((ext_vector_type(8))) _Float16 f16x8;
typedef __attribute__((ext_vector_type(4))) float f32x4;

DEVFN float shxor(float v, int m) { return __shfl_xor(v, m, 64); }

// ---------------------------------------------------------------------------
// Gate machinery (verified R1/R3/R4/R5).
// State layout: amplitude index a (8 bits) = lane*4 + k; wire w <-> bit 7-w.
// ---------------------------------------------------------------------------
template<int W>
DEVFN void rot_gate(int lane, float (&sr)[4], float (&si)[4], const float* u) {
  const float u00r=u[0], u00i=u[1], u01r=u[2], u01i=u[3];
  const float u10r=u[4], u10i=u[5], u11r=u[6], u11i=u[7];
  if constexpr (W <= 5) {
    constexpr int M = 1 << (5 - W);
    const bool hi = (lane & M) != 0;
    const float cmr = hi ? u11r : u00r, cmi = hi ? u11i : u00i;
    const float cor = hi ? u10r : u01r, coi = hi ? u10i : u01i;
    #pragma unroll
    for (int k = 0; k < 4; ++k) {
      float orr = shxor(sr[k], M);
      float oii = shxor(si[k], M);
      float nr = cmr*sr[k] - cmi*si[k] + cor*orr - coi*oii;
      float ni = cmr*si[k] + cmi*sr[k] + cor*oii + coi*orr;
      sr[k] = nr; si[k] = ni;
    }
  } else {
    constexpr int KB = (W == 6) ? 2 : 1;
    #pragma unroll
    for (int k0 = 0; k0 < 4; ++k0) {
      if ((k0 & KB) == 0) {
        const int k1 = k0 | KB;
        float ar = sr[k0], ai = si[k0];
        float br = sr[k1], bi = si[k1];
        sr[k0] = u00r*ar - u00i*ai + u01r*br - u01i*bi;
        si[k0] = u00r*ai + u00i*ar + u01r*bi + u01i*br;
        sr[k1] = u10r*ar - u10i*ai + u11r*br - u11i*bi;
        si[k1] = u10r*ai + u10i*ar + u11r*bi + u11i*br;
      }
    }
  }
}

template<int C, int T>
DEVFN void cnot_gate(int lane, float (&sr)[4], float (&si)[4]) {
  constexpr int PC = 7 - C, PT = 7 - T;
  if constexpr (PT >= 2) {
    constexpr int M = 1 << (PT - 2);
    #pragma unroll
    for (int k = 0; k < 4; ++k) {
      float orr = shxor(sr[k], M);
      float oii = shxor(si[k], M);
      bool ctrl;
      if constexpr (PC >= 2) ctrl = ((lane >> (PC - 2)) & 1) != 0;
      else                   ctrl = ((k >> PC) & 1) != 0;
      if (ctrl) { sr[k] = orr; si[k] = oii; }
    }
  } else {
    float tr[4], ti[4];
    #pragma unroll
    for (int k = 0; k < 4; ++k) { tr[k] = sr[k]; ti[k] = si[k]; }
    #pragma unroll
    for (int k = 0; k < 4; ++k) {
      bool ctrl;
      if constexpr (PC >= 2) ctrl = ((lane >> (PC - 2)) & 1) != 0;
      else                   ctrl = ((k >> PC) & 1) != 0;
      if (ctrl) { sr[k] = tr[k ^ (1 << PT)]; si[k] = ti[k ^ (1 << PT)]; }
    }
  }
}

// ---------------------------------------------------------------------------
// Prep (identical to validated R5): blocks 0..255 simulate basis state e_col
// and scatter into per-wave MFMA fragment layout:
//   Bfrag[((ch*4 + q)*8 + ks)*512 + (kg*16 + cf)*8 + e]
//   amp a: ch=a>>5, nf=(a>>4)&1, cf=a&15; q = nf (Re) / 2+nf (Im);
//   col j: ks=j>>5, kg=(j>>3)&3, e=j&7.
// Block 256: folded LayerNorm/FC stats.
// ---------------------------------------------------------------------------
__global__ __launch_bounds__(64) void qsb_prep(
    const float* __restrict__ qw, const float* __restrict__ Wm,
    const float* __restrict__ bias,
    _Float16* __restrict__ Bfrag, float* __restrict__ stats) {
  __shared__ float uL[16 * 8];
  int bid = blockIdx.x;
  int lane = threadIdx.x;
  if (bid < 256) {
    if (lane < 16) {
      int l = lane >> 3, i = lane & 7;
      float phi = qw[l*24 + i*3 + 0];
      float th  = qw[l*24 + i*3 + 1];
      float om  = qw[l*24 + i*3 + 2];
      float cth = cosf(0.5f*th), sth = sinf(0.5f*th);
      float ap = 0.5f*(phi+om), am = 0.5f*(phi-om);
      float cap = cosf(ap), sap = sinf(ap);
      float cam = cosf(am), sam = sinf(am);
      float* u = &uL[lane*8];
      u[0] =  cap*cth; u[1] = -sap*cth;
      u[2] = -cam*sth; u[3] = -sam*sth;
      u[4] =  cam*sth; u[5] = -sam*sth;
      u[6] =  cap*cth; u[7] =  sap*cth;
    }
    __syncthreads();
    int col = bid;
    float sr[4], si[4];
    #pragma unroll
    for (int k = 0; k < 4; ++k) { sr[k] = (lane*4 + k == col) ? 1.f : 0.f; si[k] = 0.f; }
    rot_gate<0>(lane, sr, si, &uL[0*8]);
    rot_gate<1>(lane, sr, si, &uL[1*8]);
    rot_gate<2>(lane, sr, si, &uL[2*8]);
    rot_gate<3>(lane, sr, si, &uL[3*8]);
    rot_gate<4>(lane, sr, si, &uL[4*8]);
    rot_gate<5>(lane, sr, si, &uL[5*8]);
    rot_gate<6>(lane, sr, si, &uL[6*8]);
    rot_gate<7>(lane, sr, si, &uL[7*8]);
    cnot_gate<0,1>(lane, sr, si);
    cnot_gate<1,2>(lane, sr, si);
    cnot_gate<2,3>(lane, sr, si);
    cnot_gate<3,4>(lane, sr, si);
    cnot_gate<4,5>(lane, sr, si);
    cnot_gate<5,6>(lane, sr, si);
    cnot_gate<6,7>(lane, sr, si);
    cnot_gate<7,0>(lane, sr, si);
    rot_gate<0>(lane, sr, si, &uL[(8+0)*8]);
    rot_gate<1>(lane, sr, si, &uL[(8+1)*8]);
    rot_gate<2>(lane, sr, si, &uL[(8+2)*8]);
    rot_gate<3>(lane, sr, si, &uL[(8+3)*8]);
    rot_gate<4>(lane, sr, si, &uL[(8+4)*8]);
    rot_gate<5>(lane, sr, si, &uL[(8+5)*8]);
    rot_gate<6>(lane, sr, si, &uL[(8+6)*8]);
    rot_gate<7>(lane, sr, si, &uL[(8+7)*8]);
    cnot_gate<0,2>(lane, sr, si);
    cnot_gate<1,3>(lane, sr, si);
    cnot_gate<2,4>(lane, sr, si);
    cnot_gate<3,5>(lane, sr, si);
    cnot_gate<4,6>(lane, sr, si);
    cnot_gate<5,7>(lane, sr, si);
    cnot_gate<6,0>(lane, sr, si);
    cnot_gate<7,1>(lane, sr, si);
    const int ks = col >> 5, kg = (col >> 3) & 3, e = col & 7;
    #pragma unroll
    for (int k = 0; k < 4; ++k) {
      int a = lane*4 + k;
      int ch = a >> 5, nf = (a >> 4) & 1, cf = a & 15;
      int pos = (kg*16 + cf)*8 + e;
      Bfrag[((ch*4 + nf    )*8 + ks)*512 + pos] = (_Float16)sr[k];
      Bfrag[((ch*4 + 2 + nf)*8 + ks)*512 + pos] = (_Float16)si[k];
    }
  } else {
    int t = lane;
    {
      int i = t >> 3, j = t & 7;
      float s = 0.f;
      for (int c = 0; c < 64; ++c) s += Wm[i*64 + c] * Wm[j*64 + c];
      stats[16 + t] = s * 0.015625f;
    }
    if (t < 8) {
      float s = 0.f, sb = 0.f;
      for (int c = 0; c < 64; ++c) { float w = Wm[t*64 + c]; s += w; sb += w * bias[c]; }
      stats[t]     = s * 0.015625f;
      stats[8 + t] = 2.f * sb * 0.015625f;
    }
    if (t == 0) {
      float s = 0.f, s2 = 0.f;
      for (int c = 0; c < 64; ++c) { s += bias[c]; s2 += bias[c]*bias[c]; }
      stats[80] = s * 0.015625f;
      stats[81] = s2 * 0.015625f;
    }
  }
}

// ---------------------------------------------------------------------------
// Main: 32 rows/block, 256 threads (4 waves), grid = B/32 = 1024 blocks.
// Wave wid handles chunks {2*wid, 2*wid+1}; per chunk: M=32 x N=64 x K=256
// GEMM (64 MFMAs), then probs -> wave-private LDS transpose -> 2 MFMAs
// against sign matrix S -> zpart. Z combine / LN stats / FC+GELU are
// wave-local. 2 __syncthreads() total.
// Amp bits: b7b6b5 = chunk, b4 = nf, b3..b0 = cf; wire w <-> bit 7-w.
// ---------------------------------------------------------------------------
__global__ __launch_bounds__(256, 4) void qsb_main(
    const float* __restrict__ pca, const _Float16* __restrict__ Bfrag,
    const float* __restrict__ statsG,
    const float* __restrict__ Wm, const float* __restrict__ bias,
    const float* __restrict__ gamma, const float* __restrict__ beta,
    float* __restrict__ out, int B) {
  // A3: element (row,k): ((ks*2 + m)*16 + cf)*32 + (kg^(ks&3))*8 + e
  //   ks=k>>5, kg=(k>>3)&3, e=k&7, m=row>>4, cf=row&15  (16 KB)
  __shared__ __align__(16) _Float16 A3[8192];
  // Y: per-wave 2 m-tiles x 16 rows x stride 40 f16 (10 KB)
  __shared__ __align__(16) _Float16 YL[4 * 1280];
  __shared__ float zpart[2304];   // [ch=8][row=32][9], slots 0..5 used (9 KB)
  __shared__ float zrow[256];     // [row=32][8]
  __shared__ float musig[64];     // [row=32][2]
  __shared__ float Wl[512];
  __shared__ float biasL[64], gammaL[64], betaL[64];
  __shared__ float statsL[82];

  const int tid = threadIdx.x;
  const int wid = tid >> 6, lane = tid & 63;
  const int cfrag = lane & 15, kgrp = lane >> 4;
  const int r0 = blockIdx.x * 32;

  // ---- phase 0: preloads (FIX: cover all 512 Wl entries with 256 threads) ----
  #pragma unroll
  for (int i = tid; i < 512; i += 256) Wl[i] = Wm[i];
  if (tid >= 256 - 64) {
    int t = tid - (256 - 64);
    biasL[t] = bias[t]; gammaL[t] = gamma[t]; betaL[t] = beta[t];
  }
  if (tid < 82) statsL[tid] = statsG[tid];

  // ---- sign fragment for the S-MFMA (B-frag: col=cfrag, k=kgrp*8+e) ----
  f16x8 sfrag;
  #pragma unroll
  for (int e = 0; e < 8; ++e) {
    float v;
    if      (cfrag == 0) v = 1.f;                        // T (chunk total)
    else if (cfrag == 1) v = (kgrp & 2) ? -1.f : 1.f;    // wire 3 (a bit4)
    else if (cfrag == 2) v = (kgrp & 1) ? -1.f : 1.f;    // wire 4 (a bit3)
    else if (cfrag == 3) v = (e & 4)    ? -1.f : 1.f;    // wire 5 (a bit2)
    else if (cfrag == 4) v = (e & 2)    ? -1.f : 1.f;    // wire 6 (a bit1)
    else if (cfrag == 5) v = (e & 1)    ? -1.f : 1.f;    // wire 7 (a bit0)
    else v = 0.f;
    sfrag[e] = (_Float16)v;
  }

  // ---- phase 1: A build (8 threads/row, 32 k each), fast trig ----
  {
    const int rl = tid >> 3, tq = tid & 7;
    const int r = r0 + rl;
    float cv[8], sv[8];
    #pragma unroll
    for (int w = 0; w < 8; ++w) { cv[w] = 1.f; sv[w] = 0.f; }
    if (r < B) {
      #pragma unroll
      for (int w = 0; w < 8; ++w) {
        float x = pca[r*8 + w];
        float sg = __builtin_amdgcn_rcpf(1.f + __expf(-x));
        float ang = 1.5707963267948966f * sg;
        cv[w] = __cosf(ang); sv[w] = __sinf(ang);
      }
    }
    float base = ((tq & 4) ? sv[0] : cv[0]) * ((tq & 2) ? sv[1] : cv[1])
               * ((tq & 1) ? sv[2] : cv[2]);
    float arr[32];
    arr[0] = base;
    #pragma unroll
    for (int p = 0; p < 5; ++p) {
      const int w = 7 - p;
      const int sz = 1 << p;
      #pragma unroll
      for (int i = 0; i < (1 << p); ++i) {
        arr[i + sz] = arr[i] * sv[w];
        arr[i]      = arr[i] * cv[w];
      }
    }
    _Float16* dstBase = &A3[((tq*2 + (rl >> 4))*16 + (rl & 15))*32];
    #pragma unroll
    for (int ib = 0; ib < 4; ++ib) {
      f16x8 v;
      #pragma unroll
      for (int j = 0; j < 8; ++j) v[j] = (_Float16)arr[ib*8 + j];
      *(f16x8*)(dstBase + (ib ^ (tq & 3))*8) = v;
    }
  }
  __syncthreads();   // barrier 1: A3 ready

  // ---- phases 2+3, per chunk ----
  _Float16* Yw = &YL[wid * 1280];
  #pragma unroll
  for (int c = 0; c < 2; ++c) {
    const int ch = wid*2 + c;
    const _Float16* Bw = Bfrag + (size_t)(ch*4)*8*512 + lane*8;

    f32x4 acc[2][4];
    #pragma unroll
    for (int m = 0; m < 2; ++m)
      #pragma unroll
      for (int q = 0; q < 4; ++q) acc[m][q] = (f32x4){0.f, 0.f, 0.f, 0.f};

    f16x8 bqA[4], bqB[4];
    #pragma unroll
    for (int q = 0; q < 4; ++q) bqA[q] = *(const f16x8*)(Bw + (q*8 + 0)*512);

    #pragma unroll
    for (int kp = 0; kp < 4; ++kp) {
      const int ks0 = kp*2, ks1 = kp*2 + 1;
      #pragma unroll
      for (int q = 0; q < 4; ++q) bqB[q] = *(const f16x8*)(Bw + (q*8 + ks1)*512);
      {
        f16x8 af0 = *(const f16x8*)&A3[((ks0*2 + 0)*16 + cfrag)*32 + (kgrp ^ (ks0 & 3))*8];
        f16x8 af1 = *(const f16x8*)&A3[((ks0*2 + 1)*16 + cfrag)*32 + (kgrp ^ (ks0 & 3))*8];
        #pragma unroll
        for (int q = 0; q < 4; ++q) {
          acc[0][q] = __builtin_amdgcn_mfma_f32_16x16x32_f16(af0, bqA[q], acc[0][q], 0, 0, 0);
          acc[1][q] = __builtin_amdgcn_mfma_f32_16x16x32_f16(af1, bqA[q], acc[1][q], 0, 0, 0);
        }
      }
      if (kp < 3) {
        #pragma unroll
        for (int q = 0; q < 4; ++q) bqA[q] = *(const f16x8*)(Bw + (q*8 + ks0 + 2)*512);
      }
      {
        f16x8 af0 = *(const f16x8*)&A3[((ks1*2 + 0)*16 + cfrag)*32 + (kgrp ^ (ks1 & 3))*8];
        f16x8 af1 = *(const f16x8*)&A3[((ks1*2 + 1)*16 + cfrag)*32 + (kgrp ^ (ks1 & 3))*8];
        #pragma unroll
        for (int q = 0; q < 4; ++q) {
          acc[0][q] = __builtin_amdgcn_mfma_f32_16x16x32_f16(af0, bqB[q], acc[0][q], 0, 0, 0);
          acc[1][q] = __builtin_amdgcn_mfma_f32_16x16x32_f16(af1, bqB[q], acc[1][q], 0, 0, 0);
        }
      }
    }

    // probs -> wave-private Y (f16, A-frag-transposed via LDS, stride 40)
    #pragma unroll
    for (int m = 0; m < 2; ++m) {
      #pragma unroll
      for (int nf = 0; nf < 2; ++nf) {
        #pragma unroll
        for (int j = 0; j < 4; ++j) {
          float re = acc[m][nf][j], im = acc[m][2 + nf][j];
          float p = re*re + im*im;
          Yw[m*640 + (kgrp*4 + j)*40 + nf*16 + cfrag] = (_Float16)p;
        }
      }
    }
    // wave-private read-back (in-order DS pipe; no barrier needed)
    #pragma unroll
    for (int m = 0; m < 2; ++m) {
      f16x8 yfrag = *(const f16x8*)&Yw[m*640 + (lane & 15)*40 + kgrp*8];
      f32x4 d = __builtin_amdgcn_mfma_f32_16x16x32_f16(yfrag, sfrag, (f32x4){0.f,0.f,0.f,0.f}, 0, 0, 0);
      if (cfrag < 6) {
        #pragma unroll
        for (int j = 0; j < 4; ++j)
          zpart[(ch*32 + m*16 + kgrp*4 + j)*9 + cfrag] = d[j];
      }
    }
  }
  __syncthreads();   // barrier 2: zpart ready

  // ---- phase 4+5: combine chunks + LN stats (wave-local, thread=(row,wire)) ----
  {
    const int row = tid >> 3, w = tid & 7;
    const int slot = (w < 3) ? 0 : (w - 2);
    const int sm = (w == 0) ? 4 : (w == 1) ? 2 : (w == 2) ? 1 : 0;
    float z = 0.f;
    #pragma unroll
    for (int ch = 0; ch < 8; ++ch) {
      float v = zpart[(ch*32 + row)*9 + slot];
      z += (ch & sm) ? -v : v;
    }
    zrow[row*8 + w] = z;
    // same wave wrote all 8 slots of this row -> in-order DS, read back
    f32x4 zlo = *(const f32x4*)&zrow[row*8];
    f32x4 zhi = *(const f32x4*)&zrow[row*8 + 4];
    float zj[8] = {zlo[0], zlo[1], zlo[2], zlo[3], zhi[0], zhi[1], zhi[2], zhi[3]};
    float qi = statsL[8 + w];
    #pragma unroll
    for (int j = 0; j < 8; ++j) qi += statsL[16 + w*8 + j] * zj[j];
    float e2p = zj[w] * qi;
    float mup = statsL[w] * zj[w];
    e2p += shxor(e2p, 1); e2p += shxor(e2p, 2); e2p += shxor(e2p, 4);
    mup += shxor(mup, 1); mup += shxor(mup, 2); mup += shxor(mup, 4);
    if (w == 0) {
      float mu = mup + statsL[80];
      float e2 = e2p + statsL[81];
      float var = e2 - mu*mu;
      musig[row*2]     = mu;
      musig[row*2 + 1] = rsqrtf(fmaxf(var, 0.f) + 1e-5f);
    }
  }
  // no barrier: phase 6 reads only this wave's zrow/musig rows

  // ---- phase 6: FC + LN + exact GELU (8 rows per wave) ----
  #pragma unroll
  for (int rr = 0; rr < 8; ++rr) {
    const int row = wid*8 + rr;
    const int gr = r0 + row;
    float h = biasL[lane];
    #pragma unroll
    for (int i = 0; i < 8; ++i) h = fmaf(zrow[row*8 + i], Wl[i*64 + lane], h);
    float hn = (h - musig[row*2]) * musig[row*2 + 1] * gammaL[lane] + betaL[lane];
    float ge = 0.5f * hn * (1.f + erff(hn * 0.70710678118654752f));
    if (gr < B) out[gr*64 + lane] = ge;
  }
}

extern "C" void kernel_launch(void* const* d_in, const int* in_sizes, int n_in,
                              void* d_out, int out_size, void* d_ws, size_t ws_size,
                              hipStream_t stream) {
  const float* pca   = (const float*)d_in[0];
  const float* qw    = (const float*)d_in[1];
  const float* Wm    = (const float*)d_in[2];
  const float* bias  = (const float*)d_in[3];
  const float* gamma = (const float*)d_in[4];
  const float* beta  = (const float*)d_in[5];
  float* out = (float*)d_out;

  _Float16* Bfrag = (_Float16*)d_ws;                   // 512*256*2 = 256 KiB
  float* stats = (float*)((char*)d_ws + 512*256*2);    // 82 floats

  int B = in_sizes[0] / 8;

  hipLaunchKernelGGL(qsb_prep, dim3(257), dim3(64), 0, stream, qw, Wm, bias, Bfrag, stats);
  int blocks = (B + 31) / 32;
  hipLaunchKernelGGL(qsb_main, dim3(blocks), dim3(256), 0, stream,
                     pca, Bfrag, stats, Wm, bias, gamma, beta, out, B);
}

// Round 8
// 28.578 us; speedup vs baseline: 3.3953x; 1.0000x over previous
//
#include <hip/hip_runtime.h>
#include <math.h>

#define DEVFN __device__ __forceinline__

typedef __attribute__((ext_vector_type(8))) _Float16 f16x8;
typedef __attribute__((ext_vector_type(4))) float f32x4;

DEVFN float shxor(float v, int m) { return __shfl_xor(v, m, 64); }

// ---------------------------------------------------------------------------
// Gate machinery (verified R1/R3/R4/R5).
// State layout: amplitude index a (8 bits) = lane*4 + k; wire w <-> bit 7-w.
// ---------------------------------------------------------------------------
template<int W>
DEVFN void rot_gate(int lane, float (&sr)[4], float (&si)[4], const float* u) {
  const float u00r=u[0], u00i=u[1], u01r=u[2], u01i=u[3];
  const float u10r=u[4], u10i=u[5], u11r=u[6], u11i=u[7];
  if constexpr (W <= 5) {
    constexpr int M = 1 << (5 - W);
    const bool hi = (lane & M) != 0;
    const float cmr = hi ? u11r : u00r, cmi = hi ? u11i : u00i;
    const float cor = hi ? u10r : u01r, coi = hi ? u10i : u01i;
    #pragma unroll
    for (int k = 0; k < 4; ++k) {
      float orr = shxor(sr[k], M);
      float oii = shxor(si[k], M);
      float nr = cmr*sr[k] - cmi*si[k] + cor*orr - coi*oii;
      float ni = cmr*si[k] + cmi*sr[k] + cor*oii + coi*orr;
      sr[k] = nr; si[k] = ni;
    }
  } else {
    constexpr int KB = (W == 6) ? 2 : 1;
    #pragma unroll
    for (int k0 = 0; k0 < 4; ++k0) {
      if ((k0 & KB) == 0) {
        const int k1 = k0 | KB;
        float ar = sr[k0], ai = si[k0];
        float br = sr[k1], bi = si[k1];
        sr[k0] = u00r*ar - u00i*ai + u01r*br - u01i*bi;
        si[k0] = u00r*ai + u00i*ar + u01r*bi + u01i*br;
        sr[k1] = u10r*ar - u10i*ai + u11r*br - u11i*bi;
        si[k1] = u10r*ai + u10i*ar + u11r*bi + u11i*br;
      }
    }
  }
}

template<int C, int T>
DEVFN void cnot_gate(int lane, float (&sr)[4], float (&si)[4]) {
  constexpr int PC = 7 - C, PT = 7 - T;
  if constexpr (PT >= 2) {
    constexpr int M = 1 << (PT - 2);
    #pragma unroll
    for (int k = 0; k < 4; ++k) {
      float orr = shxor(sr[k], M);
      float oii = shxor(si[k], M);
      bool ctrl;
      if constexpr (PC >= 2) ctrl = ((lane >> (PC - 2)) & 1) != 0;
      else                   ctrl = ((k >> PC) & 1) != 0;
      if (ctrl) { sr[k] = orr; si[k] = oii; }
    }
  } else {
    float tr[4], ti[4];
    #pragma unroll
    for (int k = 0; k < 4; ++k) { tr[k] = sr[k]; ti[k] = si[k]; }
    #pragma unroll
    for (int k = 0; k < 4; ++k) {
      bool ctrl;
      if constexpr (PC >= 2) ctrl = ((lane >> (PC - 2)) & 1) != 0;
      else                   ctrl = ((k >> PC) & 1) != 0;
      if (ctrl) { sr[k] = tr[k ^ (1 << PT)]; si[k] = ti[k ^ (1 << PT)]; }
    }
  }
}

// ---------------------------------------------------------------------------
// Prep (identical to validated R5/R7): blocks 0..255 simulate basis state
// e_col and scatter into per-wave MFMA fragment layout:
//   Bfrag[((ch*4 + q)*8 + ks)*512 + (kg*16 + cf)*8 + e]
// Block 256: folded LayerNorm/FC stats.
// ---------------------------------------------------------------------------
__global__ __launch_bounds__(64) void qsb_prep(
    const float* __restrict__ qw, const float* __restrict__ Wm,
    const float* __restrict__ bias,
    _Float16* __restrict__ Bfrag, float* __restrict__ stats) {
  __shared__ float uL[16 * 8];
  int bid = blockIdx.x;
  int lane = threadIdx.x;
  if (bid < 256) {
    if (lane < 16) {
      int l = lane >> 3, i = lane & 7;
      float phi = qw[l*24 + i*3 + 0];
      float th  = qw[l*24 + i*3 + 1];
      float om  = qw[l*24 + i*3 + 2];
      float cth = cosf(0.5f*th), sth = sinf(0.5f*th);
      float ap = 0.5f*(phi+om), am = 0.5f*(phi-om);
      float cap = cosf(ap), sap = sinf(ap);
      float cam = cosf(am), sam = sinf(am);
      float* u = &uL[lane*8];
      u[0] =  cap*cth; u[1] = -sap*cth;
      u[2] = -cam*sth; u[3] = -sam*sth;
      u[4] =  cam*sth; u[5] = -sam*sth;
      u[6] =  cap*cth; u[7] =  sap*cth;
    }
    __syncthreads();
    int col = bid;
    float sr[4], si[4];
    #pragma unroll
    for (int k = 0; k < 4; ++k) { sr[k] = (lane*4 + k == col) ? 1.f : 0.f; si[k] = 0.f; }
    rot_gate<0>(lane, sr, si, &uL[0*8]);
    rot_gate<1>(lane, sr, si, &uL[1*8]);
    rot_gate<2>(lane, sr, si, &uL[2*8]);
    rot_gate<3>(lane, sr, si, &uL[3*8]);
    rot_gate<4>(lane, sr, si, &uL[4*8]);
    rot_gate<5>(lane, sr, si, &uL[5*8]);
    rot_gate<6>(lane, sr, si, &uL[6*8]);
    rot_gate<7>(lane, sr, si, &uL[7*8]);
    cnot_gate<0,1>(lane, sr, si);
    cnot_gate<1,2>(lane, sr, si);
    cnot_gate<2,3>(lane, sr, si);
    cnot_gate<3,4>(lane, sr, si);
    cnot_gate<4,5>(lane, sr, si);
    cnot_gate<5,6>(lane, sr, si);
    cnot_gate<6,7>(lane, sr, si);
    cnot_gate<7,0>(lane, sr, si);
    rot_gate<0>(lane, sr, si, &uL[(8+0)*8]);
    rot_gate<1>(lane, sr, si, &uL[(8+1)*8]);
    rot_gate<2>(lane, sr, si, &uL[(8+2)*8]);
    rot_gate<3>(lane, sr, si, &uL[(8+3)*8]);
    rot_gate<4>(lane, sr, si, &uL[(8+4)*8]);
    rot_gate<5>(lane, sr, si, &uL[(8+5)*8]);
    rot_gate<6>(lane, sr, si, &uL[(8+6)*8]);
    rot_gate<7>(lane, sr, si, &uL[(8+7)*8]);
    cnot_gate<0,2>(lane, sr, si);
    cnot_gate<1,3>(lane, sr, si);
    cnot_gate<2,4>(lane, sr, si);
    cnot_gate<3,5>(lane, sr, si);
    cnot_gate<4,6>(lane, sr, si);
    cnot_gate<5,7>(lane, sr, si);
    cnot_gate<6,0>(lane, sr, si);
    cnot_gate<7,1>(lane, sr, si);
    const int ks = col >> 5, kg = (col >> 3) & 3, e = col & 7;
    #pragma unroll
    for (int k = 0; k < 4; ++k) {
      int a = lane*4 + k;
      int ch = a >> 5, nf = (a >> 4) & 1, cf = a & 15;
      int pos = (kg*16 + cf)*8 + e;
      Bfrag[((ch*4 + nf    )*8 + ks)*512 + pos] = (_Float16)sr[k];
      Bfrag[((ch*4 + 2 + nf)*8 + ks)*512 + pos] = (_Float16)si[k];
    }
  } else {
    int t = lane;
    {
      int i = t >> 3, j = t & 7;
      float s = 0.f;
      for (int c = 0; c < 64; ++c) s += Wm[i*64 + c] * Wm[j*64 + c];
      stats[16 + t] = s * 0.015625f;
    }
    if (t < 8) {
      float s = 0.f, sb = 0.f;
      for (int c = 0; c < 64; ++c) { float w = Wm[t*64 + c]; s += w; sb += w * bias[c]; }
      stats[t]     = s * 0.015625f;
      stats[8 + t] = 2.f * sb * 0.015625f;
    }
    if (t == 0) {
      float s = 0.f, s2 = 0.f;
      for (int c = 0; c < 64; ++c) { s += bias[c]; s2 += bias[c]*bias[c]; }
      stats[80] = s * 0.015625f;
      stats[81] = s2 * 0.015625f;
    }
  }
}

// ---------------------------------------------------------------------------
// Main: 32 rows/block, 256 threads (4 waves), grid = B/32 = 1024 blocks.
// Wave wid handles chunks {2*wid, 2*wid+1} flattened into 16 half-steps
// (c = s>>3, ks = s&7). B loads run a depth-8 pipeline: 3 rotating register
// banks of 4 fragments; loads for step s+2 are issued BEFORE the MFMAs of
// step s, so >=8 x 1KB loads stay in flight (incl. across chunk epilogues).
// Chunk epilogue: probs -> wave-private LDS transpose -> S-MFMA -> zpart.
// Amp bits: b7b6b5 = chunk, b4 = nf, b3..b0 = cf; wire w <-> bit 7-w.
// ---------------------------------------------------------------------------
__global__ __launch_bounds__(256, 4) void qsb_main(
    const float* __restrict__ pca, const _Float16* __restrict__ Bfrag,
    const float* __restrict__ statsG,
    const float* __restrict__ Wm, const float* __restrict__ bias,
    const float* __restrict__ gamma, const float* __restrict__ beta,
    float* __restrict__ out, int B) {
  // A3: element (row,k): ((ks*2 + m)*16 + cf)*32 + (kg^(ks&3))*8 + e  (16 KB)
  __shared__ __align__(16) _Float16 A3[8192];
  __shared__ __align__(16) _Float16 YL[4 * 1280];  // per-wave Y, stride 40 (10 KB)
  __shared__ float zpart[2304];   // [ch=8][row=32][9], slots 0..5 used (9 KB)
  __shared__ float zrow[256];     // [row=32][8]
  __shared__ float musig[64];     // [row=32][2]
  __shared__ float Wl[512];
  __shared__ float biasL[64], gammaL[64], betaL[64];
  __shared__ float statsL[82];

  const int tid = threadIdx.x;
  const int wid = tid >> 6, lane = tid & 63;
  const int cfrag = lane & 15, kgrp = lane >> 4;
  const int r0 = blockIdx.x * 32;

  // ---- phase 0: preloads ----
  #pragma unroll
  for (int i = tid; i < 512; i += 256) Wl[i] = Wm[i];
  if (tid >= 256 - 64) {
    int t = tid - (256 - 64);
    biasL[t] = bias[t]; gammaL[t] = gamma[t]; betaL[t] = beta[t];
  }
  if (tid < 82) statsL[tid] = statsG[tid];

  // ---- sign fragment for the S-MFMA (B-frag: col=cfrag, k=kgrp*8+e) ----
  f16x8 sfrag;
  #pragma unroll
  for (int e = 0; e < 8; ++e) {
    float v;
    if      (cfrag == 0) v = 1.f;                        // T (chunk total)
    else if (cfrag == 1) v = (kgrp & 2) ? -1.f : 1.f;    // wire 3 (a bit4)
    else if (cfrag == 2) v = (kgrp & 1) ? -1.f : 1.f;    // wire 4 (a bit3)
    else if (cfrag == 3) v = (e & 4)    ? -1.f : 1.f;    // wire 5 (a bit2)
    else if (cfrag == 4) v = (e & 2)    ? -1.f : 1.f;    // wire 6 (a bit1)
    else if (cfrag == 5) v = (e & 1)    ? -1.f : 1.f;    // wire 7 (a bit0)
    else v = 0.f;
    sfrag[e] = (_Float16)v;
  }

  // ---- phase 1: A build (8 threads/row, 32 k each), fast trig ----
  {
    const int rl = tid >> 3, tq = tid & 7;
    const int r = r0 + rl;
    float cv[8], sv[8];
    #pragma unroll
    for (int w = 0; w < 8; ++w) { cv[w] = 1.f; sv[w] = 0.f; }
    if (r < B) {
      #pragma unroll
      for (int w = 0; w < 8; ++w) {
        float x = pca[r*8 + w];
        float sg = __builtin_amdgcn_rcpf(1.f + __expf(-x));
        float ang = 1.5707963267948966f * sg;
        cv[w] = __cosf(ang); sv[w] = __sinf(ang);
      }
    }
    float base = ((tq & 4) ? sv[0] : cv[0]) * ((tq & 2) ? sv[1] : cv[1])
               * ((tq & 1) ? sv[2] : cv[2]);
    float arr[32];
    arr[0] = base;
    #pragma unroll
    for (int p = 0; p < 5; ++p) {
      const int w = 7 - p;
      const int sz = 1 << p;
      #pragma unroll
      for (int i = 0; i < (1 << p); ++i) {
        arr[i + sz] = arr[i] * sv[w];
        arr[i]      = arr[i] * cv[w];
      }
    }
    _Float16* dstBase = &A3[((tq*2 + (rl >> 4))*16 + (rl & 15))*32];
    #pragma unroll
    for (int ib = 0; ib < 4; ++ib) {
      f16x8 v;
      #pragma unroll
      for (int j = 0; j < 8; ++j) v[j] = (_Float16)arr[ib*8 + j];
      *(f16x8*)(dstBase + (ib ^ (tq & 3))*8) = v;
    }
  }
  __syncthreads();   // barrier 1: A3 ready

  // ---- phases 2+3: 16-half-step pipelined GEMM + per-chunk epilogue ----
  _Float16* Yw = &YL[wid * 1280];
  const _Float16* BwBase = Bfrag + (size_t)(wid*2) * 16384 + lane*8;
  // step s (0..15): c = s>>3 (chunk sel), ks = s&7; fragment q at
  //   BwBase + c*16384 + ks*512 + q*4096

  f32x4 acc[2][4];
  #pragma unroll
  for (int m = 0; m < 2; ++m)
    #pragma unroll
    for (int q = 0; q < 4; ++q) acc[m][q] = (f32x4){0.f, 0.f, 0.f, 0.f};

  f16x8 bk[3][4];   // rotating banks; all indices compile-time after unroll
  #pragma unroll
  for (int q = 0; q < 4; ++q) bk[0][q] = *(const f16x8*)(BwBase + 0*512 + q*4096);
  #pragma unroll
  for (int q = 0; q < 4; ++q) bk[1][q] = *(const f16x8*)(BwBase + 1*512 + q*4096);

  #pragma unroll
  for (int s = 0; s < 16; ++s) {
    const int ks = s & 7;
    const int bi = s % 3;
    // issue loads for step s+2 first (keeps >=8 loads in flight)
    if (s + 2 < 16) {
      const int bj = (s + 2) % 3;
      const int c2 = (s + 2) >> 3, ks2 = (s + 2) & 7;
      const _Float16* p2 = BwBase + c2*16384 + ks2*512;
      #pragma unroll
      for (int q = 0; q < 4; ++q) bk[bj][q] = *(const f16x8*)(p2 + q*4096);
    }
    // MFMAs of step s (bank bi, loaded 2 steps ago)
    {
      f16x8 af0 = *(const f16x8*)&A3[((ks*2 + 0)*16 + cfrag)*32 + (kgrp ^ (ks & 3))*8];
      f16x8 af1 = *(const f16x8*)&A3[((ks*2 + 1)*16 + cfrag)*32 + (kgrp ^ (ks & 3))*8];
      #pragma unroll
      for (int q = 0; q < 4; ++q) {
        acc[0][q] = __builtin_amdgcn_mfma_f32_16x16x32_f16(af0, bk[bi][q], acc[0][q], 0, 0, 0);
        acc[1][q] = __builtin_amdgcn_mfma_f32_16x16x32_f16(af1, bk[bi][q], acc[1][q], 0, 0, 0);
      }
    }
    // chunk epilogue after ks==7
    if (ks == 7) {
      const int ch = wid*2 + (s >> 3);
      // probs -> wave-private Y (f16, A-frag-transposed via LDS, stride 40)
      #pragma unroll
      for (int m = 0; m < 2; ++m) {
        #pragma unroll
        for (int nf = 0; nf < 2; ++nf) {
          #pragma unroll
          for (int j = 0; j < 4; ++j) {
            float re = acc[m][nf][j], im = acc[m][2 + nf][j];
            float p = re*re + im*im;
            Yw[m*640 + (kgrp*4 + j)*40 + nf*16 + cfrag] = (_Float16)p;
          }
        }
      }
      // wave-private read-back (in-order DS pipe; no barrier needed)
      #pragma unroll
      for (int m = 0; m < 2; ++m) {
        f16x8 yfrag = *(const f16x8*)&Yw[m*640 + (lane & 15)*40 + kgrp*8];
        f32x4 d = __builtin_amdgcn_mfma_f32_16x16x32_f16(yfrag, sfrag, (f32x4){0.f,0.f,0.f,0.f}, 0, 0, 0);
        if (cfrag < 6) {
          #pragma unroll
          for (int j = 0; j < 4; ++j)
            zpart[(ch*32 + m*16 + kgrp*4 + j)*9 + cfrag] = d[j];
        }
      }
      // reset accumulator for next chunk
      #pragma unroll
      for (int m = 0; m < 2; ++m)
        #pragma unroll
        for (int q = 0; q < 4; ++q) acc[m][q] = (f32x4){0.f, 0.f, 0.f, 0.f};
    }
  }
  __syncthreads();   // barrier 2: zpart ready

  // ---- phase 4+5: combine chunks + LN stats (wave-local, thread=(row,wire)) ----
  {
    const int row = tid >> 3, w = tid & 7;
    const int slot = (w < 3) ? 0 : (w - 2);
    const int sm = (w == 0) ? 4 : (w == 1) ? 2 : (w == 2) ? 1 : 0;
    float z = 0.f;
    #pragma unroll
    for (int ch = 0; ch < 8; ++ch) {
      float v = zpart[(ch*32 + row)*9 + slot];
      z += (ch & sm) ? -v : v;
    }
    zrow[row*8 + w] = z;
    // same wave wrote all 8 slots of this row -> in-order DS, read back
    f32x4 zlo = *(const f32x4*)&zrow[row*8];
    f32x4 zhi = *(const f32x4*)&zrow[row*8 + 4];
    float zj[8] = {zlo[0], zlo[1], zlo[2], zlo[3], zhi[0], zhi[1], zhi[2], zhi[3]};
    float qi = statsL[8 + w];
    #pragma unroll
    for (int j = 0; j < 8; ++j) qi += statsL[16 + w*8 + j] * zj[j];
    float e2p = zj[w] * qi;
    float mup = statsL[w] * zj[w];
    e2p += shxor(e2p, 1); e2p += shxor(e2p, 2); e2p += shxor(e2p, 4);
    mup += shxor(mup, 1); mup += shxor(mup, 2); mup += shxor(mup, 4);
    if (w == 0) {
      float mu = mup + statsL[80];
      float e2 = e2p + statsL[81];
      float var = e2 - mu*mu;
      musig[row*2]     = mu;
      musig[row*2 + 1] = rsqrtf(fmaxf(var, 0.f) + 1e-5f);
    }
  }
  // no barrier: phase 6 reads only this wave's zrow/musig rows

  // ---- phase 6: FC + LN + exact GELU (8 rows per wave) ----
  #pragma unroll
  for (int rr = 0; rr < 8; ++rr) {
    const int row = wid*8 + rr;
    const int gr = r0 + row;
    float h = biasL[lane];
    #pragma unroll
    for (int i = 0; i < 8; ++i) h = fmaf(zrow[row*8 + i], Wl[i*64 + lane], h);
    float hn = (h - musig[row*2]) * musig[row*2 + 1] * gammaL[lane] + betaL[lane];
    float ge = 0.5f * hn * (1.f + erff(hn * 0.70710678118654752f));
    if (gr < B) out[gr*64 + lane] = ge;
  }
}

extern "C" void kernel_launch(void* const* d_in, const int* in_sizes, int n_in,
                              void* d_out, int out_size, void* d_ws, size_t ws_size,
                              hipStream_t stream) {
  const float* pca   = (const float*)d_in[0];
  const float* qw    = (const float*)d_in[1];
  const float* Wm    = (const float*)d_in[2];
  const float* bias  = (const float*)d_in[3];
  const float* gamma = (const float*)d_in[4];
  const float* beta  = (const float*)d_in[5];
  float* out = (float*)d_out;

  _Float16* Bfrag = (_Float16*)d_ws;                   // 512*256*2 = 256 KiB
  float* stats = (float*)((char*)d_ws + 512*256*2);    // 82 floats

  int B = in_sizes[0] / 8;

  hipLaunchKernelGGL(qsb_prep, dim3(257), dim3(64), 0, stream, qw, Wm, bias, Bfrag, stats);
  int blocks = (B + 31) / 32;
  hipLaunchKernelGGL(qsb_main, dim3(blocks), dim3(256), 0, stream,
                     pca, Bfrag, stats, Wm, bias, gamma, beta, out, B);
}